// Round 1
// baseline (12645.581 us; speedup 1.0000x reference)
//
#include <hip/hip_runtime.h>

// ---------------------------------------------------------------------------
// DimeNet++ interaction block, fp32 baseline.
//   E = 300000 edges, T = 3000000 triplets, D = 128, D_DOWN = 64.
// Pipeline (all on `stream`, buffers: OUT = d_out, W1/W3/W4 in d_ws):
//   1. OUT = silu(x@w_kj + b_kj) * ((rbf@w_rbf1)@w_rbf2)
//   2. W3  = silu(OUT @ w_down)                       [E,64]
//   3. W4  = 0                                        [E,64]
//   4. W4 += scatter( W3[idx_kj] * ((sbf@w_sbf1)@w_sbf2), idx_ji )
//   5. W1  = silu(x@w_ji + b_ji)
//   6. W1  = silu(W4 @ w_up) + W1                     (= h0)
//   7. OUT = silu(W1@r1w1 + r1b1)
//   8. W1  = W1 + silu(OUT@r1w2 + r1b2)
//   9. OUT = silu(W1@w_bs + b_bs) + x
//  10. W1  = silu(OUT@r2w1 + r2b1)
//  11. OUT = OUT + silu(W1@r2w2 + r2b2)
//  12. W1  = silu(OUT@r3w1 + r3b1)
//  13. OUT = OUT + silu(W1@r3w2 + r3b2)
// ---------------------------------------------------------------------------

__device__ __forceinline__ float silu_f(float v) {
    return v / (1.0f + __expf(-v));
}

// Generic tall-skinny GEMM: Out[e][c] = post( silu( sum_k X[e][k]*W[k][c] + b[c] ) )
//   RBF:    multiply silu result by rbf_e[e][c] (basis embedding epilogue)
//   ADD_Z:  add Z[e][c] after activation (residual / skip)
// Per-block: TILE_E = 4096/N edges, 256 threads, per-thread 4 edges x 4 cols.
// LDS: W staged [K][N] (conflict-free b128 reads: 32 lanes sweep a 512B row),
//      X staged transposed [K][TILE_E] (reads are 2 broadcast 16B segments).
template<int K, int N, bool HAS_BIAS, bool RBF, bool ADD_Z>
__launch_bounds__(256, 2)
__global__ void gemm_act_kernel(const float* __restrict__ X,     // [E, K]
                                const float* __restrict__ W,     // [K, N]
                                const float* __restrict__ bias,  // [N] or null
                                const float* __restrict__ Z,     // [E, N] or null
                                const float* __restrict__ rbf,   // [E, 6] or null
                                const float* __restrict__ w_rbf1,// [6, 8]
                                const float* __restrict__ w_rbf2,// [8, 128]
                                float* __restrict__ Out,         // [E, N]
                                int E)
{
    constexpr int TILE_E = 4096 / N;   // 32 (N=128) or 64 (N=64)
    constexpr int NC4    = N / 4;      // column quads
    constexpr int EG     = 256 / NC4;  // edge groups
    constexpr int EPT    = TILE_E / EG;// = 4 in all instantiations
    static_assert(EPT == 4, "per-thread micro-tile must be 4x4");

    __shared__ float w_lds[K * N];
    __shared__ float x_lds[K * TILE_E];

    const int tid   = threadIdx.x;
    const int tile0 = blockIdx.x * TILE_E;

    // ---- stage W (coalesced float4, conflict-free writes) ----
    constexpr int WITER = (K * N) / (256 * 4);
    #pragma unroll
    for (int i = 0; i < WITER; ++i) {
        const int f = (tid + 256 * i) * 4;
        *(float4*)&w_lds[f] = *(const float4*)&W[f];
    }

    // ---- stage X transposed: x_lds[k*TILE_E + e]  (2-way-free writes) ----
    {
        const int e  = tid % TILE_E;
        const int kq = tid / TILE_E;           // 256/TILE_E groups
        constexpr int KQ  = 256 / TILE_E;      // 8 or 4
        constexpr int KPQ = K / KQ;            // k-span per group
        const int ge = tile0 + e;
        #pragma unroll
        for (int i = 0; i < KPQ / 4; ++i) {
            const int k = kq * KPQ + 4 * i;
            float v[4] = {0.f, 0.f, 0.f, 0.f};
            if (ge < E) *(float4*)v = *(const float4*)&X[(size_t)ge * K + k];
            x_lds[(k + 0) * TILE_E + e] = v[0];
            x_lds[(k + 1) * TILE_E + e] = v[1];
            x_lds[(k + 2) * TILE_E + e] = v[2];
            x_lds[(k + 3) * TILE_E + e] = v[3];
        }
    }
    __syncthreads();

    const int tc = tid % NC4;         // column quad index
    const int eg = tid / NC4;         // edge group
    const int e0 = eg * 4;
    const int c0 = tc * 4;

    float acc[4][4];
    #pragma unroll
    for (int a = 0; a < 4; ++a)
        #pragma unroll
        for (int b = 0; b < 4; ++b) acc[a][b] = 0.f;

    #pragma unroll 4
    for (int k = 0; k < K; ++k) {
        float wv[4], xv[4];
        *(float4*)wv = *(const float4*)&w_lds[k * N + c0];
        *(float4*)xv = *(const float4*)&x_lds[k * TILE_E + e0];
        #pragma unroll
        for (int a = 0; a < 4; ++a)
            #pragma unroll
            for (int b = 0; b < 4; ++b)
                acc[a][b] = fmaf(xv[a], wv[b], acc[a][b]);
    }

    // ---- epilogue ----
    float bv[4] = {0.f, 0.f, 0.f, 0.f};
    if (HAS_BIAS) *(float4*)bv = *(const float4*)&bias[c0];

    float rbfe[4][4];
    if (RBF) {
        // rbf_e[e][c] = sum_p ( sum_q rbf[e][q]*w_rbf1[q][p] ) * w_rbf2[p][c]
        #pragma unroll
        for (int a = 0; a < 4; ++a) {
            const int ge = tile0 + e0 + a;
            float rq[6];
            #pragma unroll
            for (int q = 0; q < 6; ++q)
                rq[q] = (ge < E) ? rbf[(size_t)ge * 6 + q] : 0.f;
            float e1[8];
            #pragma unroll
            for (int p = 0; p < 8; ++p) {
                float s = 0.f;
                #pragma unroll
                for (int q = 0; q < 6; ++q) s = fmaf(rq[q], w_rbf1[q * 8 + p], s);
                e1[p] = s;
            }
            #pragma unroll
            for (int b = 0; b < 4; ++b) {
                float s = 0.f;
                #pragma unroll
                for (int p = 0; p < 8; ++p) s = fmaf(e1[p], w_rbf2[p * 128 + c0 + b], s);
                rbfe[a][b] = s;
            }
        }
    }

    #pragma unroll
    for (int a = 0; a < 4; ++a) {
        const int ge = tile0 + e0 + a;
        if (ge < E) {
            float o[4];
            #pragma unroll
            for (int b = 0; b < 4; ++b) {
                float v = silu_f(acc[a][b] + bv[b]);
                if (RBF) v *= rbfe[a][b];
                o[b] = v;
            }
            if (ADD_Z) {
                float zv[4];
                *(float4*)zv = *(const float4*)&Z[(size_t)ge * N + c0];
                #pragma unroll
                for (int b = 0; b < 4; ++b) o[b] += zv[b];
            }
            *(float4*)&Out[(size_t)ge * N + c0] = *(float4*)o;
        }
    }
}

// Triplet stage: agg[idx_ji[t]][:] += xkjd[idx_kj[t]][:] * ((sbf[t]@w_sbf1)@w_sbf2)
// 64 triplets / block, 256 threads. sbf tile + basis weights staged in LDS.
__launch_bounds__(256, 2)
__global__ void triplet_kernel(const float* __restrict__ sbf,    // [T, 42]
                               const int* __restrict__ idx_kj,
                               const int* __restrict__ idx_ji,
                               const float* __restrict__ w_sbf1, // [42, 8]
                               const float* __restrict__ w_sbf2, // [8, 64]
                               const float* __restrict__ xkjd,   // [E, 64]
                               float* __restrict__ agg,          // [E, 64]
                               int T)
{
    constexpr int TB = 64;
    __shared__ float sbf_lds[TB * 42];
    __shared__ float e1_lds[TB * 8];
    __shared__ float w1_lds[42 * 8];
    __shared__ float w2_lds[8 * 64];

    const int tid = threadIdx.x;
    const size_t t0 = (size_t)blockIdx.x * TB;

    for (int i = tid; i < 42 * 8; i += 256) w1_lds[i] = w_sbf1[i];
    for (int i = tid; i < 8 * 64; i += 256) w2_lds[i] = w_sbf2[i];
    for (int i = tid; i < TB * 42; i += 256) sbf_lds[i] = sbf[t0 * 42 + i];
    __syncthreads();

    // e1[t][p] = sum_q sbf[t][q] * w_sbf1[q][p]   (q over 42)
    for (int i = tid; i < TB * 8; i += 256) {
        const int tl = i >> 3, p = i & 7;
        float s = 0.f;
        #pragma unroll
        for (int q = 0; q < 42; ++q)
            s = fmaf(sbf_lds[tl * 42 + q], w1_lds[q * 8 + p], s);
        e1_lds[i] = s;
    }
    __syncthreads();

    // 4 threads per triplet, 16 columns each
    const int tl = tid >> 2;
    const int c0 = (tid & 3) * 16;
    const size_t t = t0 + tl;
    if (t >= (size_t)T) return;

    const int kj = idx_kj[t];
    const int ji = idx_ji[t];

    float e1r[8];
    #pragma unroll
    for (int p = 0; p < 8; ++p) e1r[p] = e1_lds[tl * 8 + p];

    const float* xrow = xkjd + (size_t)kj * 64 + c0;
    float*       arow = agg  + (size_t)ji * 64 + c0;

    #pragma unroll
    for (int i = 0; i < 4; ++i) {
        float xv[4];
        *(float4*)xv = *(const float4*)&xrow[4 * i];
        float sv[4] = {0.f, 0.f, 0.f, 0.f};
        #pragma unroll
        for (int p = 0; p < 8; ++p) {
            float wv[4];
            *(float4*)wv = *(const float4*)&w2_lds[p * 64 + c0 + 4 * i];
            #pragma unroll
            for (int j = 0; j < 4; ++j) sv[j] = fmaf(e1r[p], wv[j], sv[j]);
        }
        #pragma unroll
        for (int j = 0; j < 4; ++j)
            atomicAdd(&arow[4 * i + j], xv[j] * sv[j]);
    }
}

extern "C" void kernel_launch(void* const* d_in, const int* in_sizes, int n_in,
                              void* d_out, int out_size, void* d_ws, size_t ws_size,
                              hipStream_t stream)
{
    const float* x      = (const float*)d_in[0];
    const float* rbf    = (const float*)d_in[1];
    const float* sbf    = (const float*)d_in[2];
    const int*   idx_kj = (const int*)d_in[3];
    const int*   idx_ji = (const int*)d_in[4];
    const float* w_rbf1 = (const float*)d_in[5];
    const float* w_rbf2 = (const float*)d_in[6];
    const float* w_sbf1 = (const float*)d_in[7];
    const float* w_sbf2 = (const float*)d_in[8];
    const float* w_kj   = (const float*)d_in[9];
    const float* b_kj   = (const float*)d_in[10];
    const float* w_ji   = (const float*)d_in[11];
    const float* b_ji   = (const float*)d_in[12];
    const float* w_down = (const float*)d_in[13];
    const float* w_up   = (const float*)d_in[14];
    const float* r1w1   = (const float*)d_in[15];
    const float* r1b1   = (const float*)d_in[16];
    const float* r1w2   = (const float*)d_in[17];
    const float* r1b2   = (const float*)d_in[18];
    const float* w_bs   = (const float*)d_in[19];
    const float* b_bs   = (const float*)d_in[20];
    const float* r2w1   = (const float*)d_in[21];
    const float* r2b1   = (const float*)d_in[22];
    const float* r2w2   = (const float*)d_in[23];
    const float* r2b2   = (const float*)d_in[24];
    const float* r3w1   = (const float*)d_in[25];
    const float* r3b1   = (const float*)d_in[26];
    const float* r3w2   = (const float*)d_in[27];
    const float* r3b2   = (const float*)d_in[28];

    const int E = in_sizes[0] / 128;
    const int T = in_sizes[2] / 42;

    float* OUT = (float*)d_out;
    float* W1  = (float*)d_ws;                                        // [E,128]
    float* W3  = (float*)((char*)d_ws + (size_t)E * 128 * 4);         // [E,64]
    float* W4  = (float*)((char*)d_ws + (size_t)E * 128 * 4
                                      + (size_t)E * 64 * 4);          // [E,64]

    const dim3 blk(256);
    const int g128 = (E + 31) / 32;   // TILE_E = 32 for N=128
    const int g64  = (E + 63) / 64;   // TILE_E = 64 for N=64
    const int gT   = (T + 63) / 64;

    // 1. OUT = silu(x@w_kj + b_kj) * rbf_e
    gemm_act_kernel<128,128,true,true,false><<<g128, blk, 0, stream>>>(
        x, w_kj, b_kj, nullptr, rbf, w_rbf1, w_rbf2, OUT, E);
    // 2. W3 = silu(OUT @ w_down)
    gemm_act_kernel<128,64,false,false,false><<<g64, blk, 0, stream>>>(
        OUT, w_down, nullptr, nullptr, nullptr, nullptr, nullptr, W3, E);
    // 3. agg = 0
    hipMemsetAsync(W4, 0, (size_t)E * 64 * 4, stream);
    // 4. triplet scatter-accumulate
    triplet_kernel<<<gT, blk, 0, stream>>>(sbf, idx_kj, idx_ji, w_sbf1, w_sbf2, W3, W4, T);
    // 5. W1 = silu(x@w_ji + b_ji)
    gemm_act_kernel<128,128,true,false,false><<<g128, blk, 0, stream>>>(
        x, w_ji, b_ji, nullptr, nullptr, nullptr, nullptr, W1, E);
    // 6. W1 = silu(W4 @ w_up) + W1
    gemm_act_kernel<64,128,false,false,true><<<g128, blk, 0, stream>>>(
        W4, w_up, nullptr, W1, nullptr, nullptr, nullptr, W1, E);
    // 7. OUT = silu(W1@r1w1 + r1b1)
    gemm_act_kernel<128,128,true,false,false><<<g128, blk, 0, stream>>>(
        W1, r1w1, r1b1, nullptr, nullptr, nullptr, nullptr, OUT, E);
    // 8. W1 = W1 + silu(OUT@r1w2 + r1b2)
    gemm_act_kernel<128,128,true,false,true><<<g128, blk, 0, stream>>>(
        OUT, r1w2, r1b2, W1, nullptr, nullptr, nullptr, W1, E);
    // 9. OUT = silu(W1@w_bs + b_bs) + x
    gemm_act_kernel<128,128,true,false,true><<<g128, blk, 0, stream>>>(
        W1, w_bs, b_bs, x, nullptr, nullptr, nullptr, OUT, E);
    // 10. W1 = silu(OUT@r2w1 + r2b1)
    gemm_act_kernel<128,128,true,false,false><<<g128, blk, 0, stream>>>(
        OUT, r2w1, r2b1, nullptr, nullptr, nullptr, nullptr, W1, E);
    // 11. OUT = OUT + silu(W1@r2w2 + r2b2)
    gemm_act_kernel<128,128,true,false,true><<<g128, blk, 0, stream>>>(
        W1, r2w2, r2b2, OUT, nullptr, nullptr, nullptr, OUT, E);
    // 12. W1 = silu(OUT@r3w1 + r3b1)
    gemm_act_kernel<128,128,true,false,false><<<g128, blk, 0, stream>>>(
        OUT, r3w1, r3b1, nullptr, nullptr, nullptr, nullptr, W1, E);
    // 13. OUT = OUT + silu(W1@r3w2 + r3b2)
    gemm_act_kernel<128,128,true,false,true><<<g128, blk, 0, stream>>>(
        W1, r3w2, r3b2, OUT, nullptr, nullptr, nullptr, OUT, E);
}

// Round 2
// 3214.534 us; speedup vs baseline: 3.9339x; 3.9339x over previous
//
#include <hip/hip_runtime.h>

// ---------------------------------------------------------------------------
// DimeNet++ interaction block, round 2: CSR gather replaces atomic scatter.
//   E = 300000 edges, T = 3000000 triplets, D = 128, D_DOWN = 64.
//
// Triplet stage (was 10.5 ms of atomics) is now:
//   cnt = histogram(idx_ji)                       (3M int atomics)
//   offsets = exclusive_scan(cnt)                 (2-level block scan)
//   csr = triplet ids grouped by idx_ji           (3M int atomics)
//   gather: 1 wave per edge, lane = column:
//     agg[e][c] = sum_{t in csr[e]} xkjd[idx_kj[t]][c] * dot42(sbf[t], wc[:,c])
//   with wc = w_sbf1 @ w_sbf2 precombined (bias-free linear maps compose).
//
// CSR scratch lives inside the W1 region (dead until step 5) -> ws unchanged.
// ---------------------------------------------------------------------------

__device__ __forceinline__ float silu_f(float v) {
    return v / (1.0f + __expf(-v));
}

// ---------------- dense GEMM + epilogue (unchanged from round 1) -----------
template<int K, int N, bool HAS_BIAS, bool RBF, bool ADD_Z>
__launch_bounds__(256, 2)
__global__ void gemm_act_kernel(const float* __restrict__ X,     // [E, K]
                                const float* __restrict__ W,     // [K, N]
                                const float* __restrict__ bias,  // [N] or null
                                const float* __restrict__ Z,     // [E, N] or null
                                const float* __restrict__ rbf,   // [E, 6] or null
                                const float* __restrict__ w_rbf1,// [6, 8]
                                const float* __restrict__ w_rbf2,// [8, 128]
                                float* __restrict__ Out,         // [E, N]
                                int E)
{
    constexpr int TILE_E = 4096 / N;
    constexpr int NC4    = N / 4;
    constexpr int EG     = 256 / NC4;
    constexpr int EPT    = TILE_E / EG;
    static_assert(EPT == 4, "per-thread micro-tile must be 4x4");

    __shared__ float w_lds[K * N];
    __shared__ float x_lds[K * TILE_E];

    const int tid   = threadIdx.x;
    const int tile0 = blockIdx.x * TILE_E;

    constexpr int WITER = (K * N) / (256 * 4);
    #pragma unroll
    for (int i = 0; i < WITER; ++i) {
        const int f = (tid + 256 * i) * 4;
        *(float4*)&w_lds[f] = *(const float4*)&W[f];
    }

    {
        const int e  = tid % TILE_E;
        const int kq = tid / TILE_E;
        constexpr int KQ  = 256 / TILE_E;
        constexpr int KPQ = K / KQ;
        const int ge = tile0 + e;
        #pragma unroll
        for (int i = 0; i < KPQ / 4; ++i) {
            const int k = kq * KPQ + 4 * i;
            float v[4] = {0.f, 0.f, 0.f, 0.f};
            if (ge < E) *(float4*)v = *(const float4*)&X[(size_t)ge * K + k];
            x_lds[(k + 0) * TILE_E + e] = v[0];
            x_lds[(k + 1) * TILE_E + e] = v[1];
            x_lds[(k + 2) * TILE_E + e] = v[2];
            x_lds[(k + 3) * TILE_E + e] = v[3];
        }
    }
    __syncthreads();

    const int tc = tid % NC4;
    const int eg = tid / NC4;
    const int e0 = eg * 4;
    const int c0 = tc * 4;

    float acc[4][4];
    #pragma unroll
    for (int a = 0; a < 4; ++a)
        #pragma unroll
        for (int b = 0; b < 4; ++b) acc[a][b] = 0.f;

    #pragma unroll 4
    for (int k = 0; k < K; ++k) {
        float wv[4], xv[4];
        *(float4*)wv = *(const float4*)&w_lds[k * N + c0];
        *(float4*)xv = *(const float4*)&x_lds[k * TILE_E + e0];
        #pragma unroll
        for (int a = 0; a < 4; ++a)
            #pragma unroll
            for (int b = 0; b < 4; ++b)
                acc[a][b] = fmaf(xv[a], wv[b], acc[a][b]);
    }

    float bv[4] = {0.f, 0.f, 0.f, 0.f};
    if (HAS_BIAS) *(float4*)bv = *(const float4*)&bias[c0];

    float rbfe[4][4];
    if (RBF) {
        #pragma unroll
        for (int a = 0; a < 4; ++a) {
            const int ge = tile0 + e0 + a;
            float rq[6];
            #pragma unroll
            for (int q = 0; q < 6; ++q)
                rq[q] = (ge < E) ? rbf[(size_t)ge * 6 + q] : 0.f;
            float e1[8];
            #pragma unroll
            for (int p = 0; p < 8; ++p) {
                float s = 0.f;
                #pragma unroll
                for (int q = 0; q < 6; ++q) s = fmaf(rq[q], w_rbf1[q * 8 + p], s);
                e1[p] = s;
            }
            #pragma unroll
            for (int b = 0; b < 4; ++b) {
                float s = 0.f;
                #pragma unroll
                for (int p = 0; p < 8; ++p) s = fmaf(e1[p], w_rbf2[p * 128 + c0 + b], s);
                rbfe[a][b] = s;
            }
        }
    }

    #pragma unroll
    for (int a = 0; a < 4; ++a) {
        const int ge = tile0 + e0 + a;
        if (ge < E) {
            float o[4];
            #pragma unroll
            for (int b = 0; b < 4; ++b) {
                float v = silu_f(acc[a][b] + bv[b]);
                if (RBF) v *= rbfe[a][b];
                o[b] = v;
            }
            if (ADD_Z) {
                float zv[4];
                *(float4*)zv = *(const float4*)&Z[(size_t)ge * N + c0];
                #pragma unroll
                for (int b = 0; b < 4; ++b) o[b] += zv[b];
            }
            *(float4*)&Out[(size_t)ge * N + c0] = *(float4*)o;
        }
    }
}

// ---------------- CSR construction -----------------------------------------

__global__ void count_kernel(const int* __restrict__ idx_ji, int* __restrict__ cnt, int T) {
    const int t = blockIdx.x * 256 + threadIdx.x;
    if (t < T) atomicAdd(&cnt[idx_ji[t]], 1);
}

// per-block (1024-item) sums
__global__ void scan_partial_kernel(const int* __restrict__ cnt, int* __restrict__ partial, int E) {
    __shared__ int red[256];
    const int tid = threadIdx.x;
    const int base = blockIdx.x * 1024 + tid * 4;
    int s = 0;
    #pragma unroll
    for (int i = 0; i < 4; ++i) {
        const int g = base + i;
        if (g < E) s += cnt[g];
    }
    red[tid] = s;
    __syncthreads();
    for (int off = 128; off > 0; off >>= 1) {
        if (tid < off) red[tid] += red[tid + off];
        __syncthreads();
    }
    if (tid == 0) partial[blockIdx.x] = red[0];
}

// exclusive scan of partial[NB] (NB <= 1024) by one block; also offsets[E]=T
__global__ void scan_block_kernel(const int* __restrict__ partial, int* __restrict__ blockoff,
                                  int NB, int* offsets, int E) {
    __shared__ int red[256];
    const int tid = threadIdx.x;
    int v[4]; int s = 0;
    #pragma unroll
    for (int i = 0; i < 4; ++i) {
        const int g = tid * 4 + i;
        v[i] = (g < NB) ? partial[g] : 0;
        s += v[i];
    }
    red[tid] = s;
    __syncthreads();
    for (int off = 1; off < 256; off <<= 1) {
        const int add = (tid >= off) ? red[tid - off] : 0;
        __syncthreads();
        red[tid] += add;
        __syncthreads();
    }
    int excl = (tid == 0) ? 0 : red[tid - 1];
    #pragma unroll
    for (int i = 0; i < 4; ++i) {
        const int g = tid * 4 + i;
        if (g < NB) blockoff[g] = excl;
        excl += v[i];
    }
    if (tid == 255) offsets[E] = red[255];
}

// final exclusive scan; writes offsets and cursor (cursor may alias cnt)
__global__ void scan_final_kernel(const int* cnt, const int* __restrict__ blockoff,
                                  int* offsets, int* cursor, int E) {
    __shared__ int red[256];
    const int tid = threadIdx.x;
    const int base = blockIdx.x * 1024 + tid * 4;
    int v[4]; int s = 0;
    #pragma unroll
    for (int i = 0; i < 4; ++i) {
        const int g = base + i;
        v[i] = (g < E) ? cnt[g] : 0;
        s += v[i];
    }
    red[tid] = s;
    __syncthreads();
    for (int off = 1; off < 256; off <<= 1) {
        const int add = (tid >= off) ? red[tid - off] : 0;
        __syncthreads();
        red[tid] += add;
        __syncthreads();
    }
    int run = blockoff[blockIdx.x] + ((tid == 0) ? 0 : red[tid - 1]);
    #pragma unroll
    for (int i = 0; i < 4; ++i) {
        const int g = base + i;
        if (g < E) { offsets[g] = run; cursor[g] = run; }
        run += v[i];
    }
}

__global__ void fill_kernel(const int* __restrict__ idx_ji, int* __restrict__ cursor,
                            int* __restrict__ csr, int T) {
    const int t = blockIdx.x * 256 + threadIdx.x;
    if (t < T) {
        const int pos = atomicAdd(&cursor[idx_ji[t]], 1);
        csr[pos] = t;
    }
}

// ---------------- gather: 1 wave per edge, lane = column --------------------
__launch_bounds__(256, 4)
__global__ void gather_kernel(const float* __restrict__ sbf,     // [T, 42]
                              const int* __restrict__ idx_kj,
                              const float* __restrict__ w_sbf1,  // [42, 8]
                              const float* __restrict__ w_sbf2,  // [8, 64]
                              const int* __restrict__ offsets,   // [E+1]
                              const int* __restrict__ csr,       // [T]
                              const float* __restrict__ xkjd,    // [E, 64]
                              float* __restrict__ agg,           // [E, 64]
                              int E)
{
    __shared__ float wc_lds[42 * 64];   // wc = w_sbf1 @ w_sbf2
    const int tid = threadIdx.x;
    for (int i = tid; i < 42 * 64; i += 256) {
        const int q = i >> 6, c = i & 63;
        float s = 0.f;
        #pragma unroll
        for (int p = 0; p < 8; ++p) s = fmaf(w_sbf1[q * 8 + p], w_sbf2[p * 64 + c], s);
        wc_lds[i] = s;
    }
    __syncthreads();

    const int lane = tid & 63;
    const int e = blockIdx.x * 4 + (tid >> 6);
    if (e >= E) return;

    float wcol[42];
    #pragma unroll
    for (int q = 0; q < 42; ++q) wcol[q] = wc_lds[q * 64 + lane];  // 2-way: free

    int j0 = __builtin_amdgcn_readfirstlane(offsets[e]);
    int j1 = __builtin_amdgcn_readfirstlane(offsets[e + 1]);

    float acc = 0.f;
    for (int j = j0; j < j1; ++j) {
        const int t  = __builtin_amdgcn_readfirstlane(csr[j]);
        const int kj = __builtin_amdgcn_readfirstlane(idx_kj[t]);
        const float* srow = sbf + (size_t)t * 42;
        float sv = 0.f;
        #pragma unroll
        for (int q = 0; q < 42; ++q) sv = fmaf(srow[q], wcol[q], sv);
        acc = fmaf(xkjd[(size_t)kj * 64 + lane], sv, acc);
    }
    agg[(size_t)e * 64 + lane] = acc;
}

// ---------------------------------------------------------------------------

extern "C" void kernel_launch(void* const* d_in, const int* in_sizes, int n_in,
                              void* d_out, int out_size, void* d_ws, size_t ws_size,
                              hipStream_t stream)
{
    const float* x      = (const float*)d_in[0];
    const float* rbf    = (const float*)d_in[1];
    const float* sbf    = (const float*)d_in[2];
    const int*   idx_kj = (const int*)d_in[3];
    const int*   idx_ji = (const int*)d_in[4];
    const float* w_rbf1 = (const float*)d_in[5];
    const float* w_rbf2 = (const float*)d_in[6];
    const float* w_sbf1 = (const float*)d_in[7];
    const float* w_sbf2 = (const float*)d_in[8];
    const float* w_kj   = (const float*)d_in[9];
    const float* b_kj   = (const float*)d_in[10];
    const float* w_ji   = (const float*)d_in[11];
    const float* b_ji   = (const float*)d_in[12];
    const float* w_down = (const float*)d_in[13];
    const float* w_up   = (const float*)d_in[14];
    const float* r1w1   = (const float*)d_in[15];
    const float* r1b1   = (const float*)d_in[16];
    const float* r1w2   = (const float*)d_in[17];
    const float* r1b2   = (const float*)d_in[18];
    const float* w_bs   = (const float*)d_in[19];
    const float* b_bs   = (const float*)d_in[20];
    const float* r2w1   = (const float*)d_in[21];
    const float* r2b1   = (const float*)d_in[22];
    const float* r2w2   = (const float*)d_in[23];
    const float* r2b2   = (const float*)d_in[24];
    const float* r3w1   = (const float*)d_in[25];
    const float* r3b1   = (const float*)d_in[26];
    const float* r3w2   = (const float*)d_in[27];
    const float* r3b2   = (const float*)d_in[28];

    const int E = in_sizes[0] / 128;
    const int T = in_sizes[2] / 42;

    float* OUT = (float*)d_out;
    float* W1  = (float*)d_ws;                                        // [E,128]
    float* W3  = (float*)((char*)d_ws + (size_t)E * 128 * 4);         // [E,64]
    float* W4  = (float*)((char*)d_ws + (size_t)E * 128 * 4
                                      + (size_t)E * 64 * 4);          // [E,64]

    // CSR scratch overlaid on W1 (dead until step 5):
    int* cnt      = (int*)W1;               // [E]  (also the fill cursor)
    int* offsets  = cnt + (E + 64);         // [E+1]
    int* partial  = offsets + (E + 64);     // [<=1024]
    int* blockoff = partial + 1024;         // [<=1024]
    int* csr      = blockoff + 1024;        // [T]

    const dim3 blk(256);
    const int g128 = (E + 31) / 32;
    const int g64  = (E + 63) / 64;
    const int gT   = (T + 255) / 256;
    const int NB   = (E + 1023) / 1024;
    const int gE4  = (E + 3) / 4;

    // 1. OUT = silu(x@w_kj + b_kj) * rbf_e
    gemm_act_kernel<128,128,true,true,false><<<g128, blk, 0, stream>>>(
        x, w_kj, b_kj, nullptr, rbf, w_rbf1, w_rbf2, OUT, E);
    // 2. W3 = silu(OUT @ w_down)
    gemm_act_kernel<128,64,false,false,false><<<g64, blk, 0, stream>>>(
        OUT, w_down, nullptr, nullptr, nullptr, nullptr, nullptr, W3, E);

    // 3. CSR build: histogram -> scan -> fill
    hipMemsetAsync(cnt, 0, (size_t)E * 4, stream);
    count_kernel<<<gT, blk, 0, stream>>>(idx_ji, cnt, T);
    scan_partial_kernel<<<NB, blk, 0, stream>>>(cnt, partial, E);
    scan_block_kernel<<<1, blk, 0, stream>>>(partial, blockoff, NB, offsets, E);
    scan_final_kernel<<<NB, blk, 0, stream>>>(cnt, blockoff, offsets, cnt, E);
    fill_kernel<<<gT, blk, 0, stream>>>(idx_ji, cnt, csr, T);

    // 4. gather-accumulate (writes every row of W4; no memset needed)
    gather_kernel<<<gE4, blk, 0, stream>>>(
        sbf, idx_kj, w_sbf1, w_sbf2, offsets, csr, W3, W4, E);

    // 5. W1 = silu(x@w_ji + b_ji)   (clobbers CSR scratch -- now dead)
    gemm_act_kernel<128,128,true,false,false><<<g128, blk, 0, stream>>>(
        x, w_ji, b_ji, nullptr, nullptr, nullptr, nullptr, W1, E);
    // 6. W1 = silu(W4 @ w_up) + W1
    gemm_act_kernel<64,128,false,false,true><<<g128, blk, 0, stream>>>(
        W4, w_up, nullptr, W1, nullptr, nullptr, nullptr, W1, E);
    // 7. OUT = silu(W1@r1w1 + r1b1)
    gemm_act_kernel<128,128,true,false,false><<<g128, blk, 0, stream>>>(
        W1, r1w1, r1b1, nullptr, nullptr, nullptr, nullptr, OUT, E);
    // 8. W1 = W1 + silu(OUT@r1w2 + r1b2)
    gemm_act_kernel<128,128,true,false,true><<<g128, blk, 0, stream>>>(
        OUT, r1w2, r1b2, W1, nullptr, nullptr, nullptr, W1, E);
    // 9. OUT = silu(W1@w_bs + b_bs) + x
    gemm_act_kernel<128,128,true,false,true><<<g128, blk, 0, stream>>>(
        W1, w_bs, b_bs, x, nullptr, nullptr, nullptr, OUT, E);
    // 10. W1 = silu(OUT@r2w1 + r2b1)
    gemm_act_kernel<128,128,true,false,false><<<g128, blk, 0, stream>>>(
        OUT, r2w1, r2b1, nullptr, nullptr, nullptr, nullptr, W1, E);
    // 11. OUT = OUT + silu(W1@r2w2 + r2b2)
    gemm_act_kernel<128,128,true,false,true><<<g128, blk, 0, stream>>>(
        W1, r2w2, r2b2, OUT, nullptr, nullptr, nullptr, OUT, E);
    // 12. W1 = silu(OUT@r3w1 + r3b1)
    gemm_act_kernel<128,128,true,false,false><<<g128, blk, 0, stream>>>(
        OUT, r3w1, r3b1, nullptr, nullptr, nullptr, nullptr, W1, E);
    // 13. OUT = OUT + silu(W1@r3w2 + r3b2)
    gemm_act_kernel<128,128,true,false,true><<<g128, blk, 0, stream>>>(
        W1, r3w2, r3b2, OUT, nullptr, nullptr, nullptr, OUT, E);
}

// Round 3
// 2953.357 us; speedup vs baseline: 4.2818x; 1.0884x over previous
//
#include <hip/hip_runtime.h>

// ---------------------------------------------------------------------------
// DimeNet++ interaction block, round 3:
//   - GEMM stack -> split-bf16 (hi+lo) MFMA, 3-pass, fp32-quality
//   - gather: wcol pinned in VGPRs (no LDS), pipelined index chain
// ---------------------------------------------------------------------------

__device__ __forceinline__ float silu_f(float v) {
    return v / (1.0f + __expf(-v));
}

__device__ __forceinline__ short f2bf(float f) {          // RNE float->bf16 bits
    unsigned u = __float_as_uint(f);
    unsigned r = u + 0x7fff + ((u >> 16) & 1);
    return (short)(r >> 16);
}
__device__ __forceinline__ float bf2f(short s) {
    return __uint_as_float(((unsigned)(unsigned short)s) << 16);
}

typedef __attribute__((ext_vector_type(8))) short bf16x8;
typedef __attribute__((ext_vector_type(4))) float f32x4;

// re1[e][p] = sum_q rbf[e][q] * w_rbf1[q][p]
__global__ void rbf1_kernel(const float* __restrict__ rbf, const float* __restrict__ w_rbf1,
                            float* __restrict__ re1, int E) {
    const int i = blockIdx.x * 256 + threadIdx.x;
    const int e = i >> 3, p = i & 7;
    if (e < E) {
        float s = 0.f;
        #pragma unroll
        for (int q = 0; q < 6; ++q) s = fmaf(rbf[e * 6 + q], w_rbf1[q * 8 + p], s);
        re1[i] = s;
    }
}

// ---------------- split-bf16 MFMA GEMM + epilogue ---------------------------
// Out[e][c] = post( silu( sum_k X[e][k]*W[k][c] + b[c] ) )
// Block: 256 threads = 4 waves, 64 rows (16/wave), all N cols.
// W staged in LDS transposed [col][plane(hi/lo)][k] bf16, XOR-swizzled chunks.
template<int K, int N, bool HAS_BIAS, bool RBF, bool ADD_Z>
__launch_bounds__(256, 2)
__global__ void gemm_mfma_kernel(const float* __restrict__ X,     // [E, K]
                                 const float* __restrict__ W,     // [K, N]
                                 const float* __restrict__ bias,  // [N] or null
                                 const float* __restrict__ Z,     // [E, N] or null
                                 const float* __restrict__ re1,   // [E, 8] or null
                                 const float* __restrict__ w_rbf2,// [8, 128] or null
                                 float* __restrict__ Out,         // [E, N]
                                 int E)
{
    constexpr int NF = N / 16;   // n-frags per wave
    constexpr int KS = K / 32;   // k-steps
    constexpr int CH = K / 8;    // 16B chunks per plane-row
    constexpr int SM = CH - 1;   // swizzle mask (15 or 7)

    __shared__ __align__(16) short b_lds[N * 2 * K];
    __shared__ float w2_lds[RBF ? 8 * 128 : 1];

    const int tid = threadIdx.x;

    // ---- stage W -> bf16 hi/lo, transposed + swizzled ----
    {
        constexpr int SEG = 256 / N;
        constexpr int KPS = K / SEG;
        const int col = tid % N;
        const int seg = tid / N;
        #pragma unroll
        for (int j = 0; j < KPS; j += 8) {
            const int kb = seg * KPS + j;
            float v[8];
            #pragma unroll
            for (int jj = 0; jj < 8; ++jj) v[jj] = W[(size_t)(kb + jj) * N + col];
            bf16x8 ah, al;
            #pragma unroll
            for (int jj = 0; jj < 8; ++jj) {
                short h = f2bf(v[jj]);
                ah[jj] = h;
                al[jj] = f2bf(v[jj] - bf2f(h));
            }
            const int ch = kb >> 3;
            const int sh = ch ^ (col & SM);
            *(bf16x8*)&b_lds[col * 2 * K + (sh << 3)]        = ah;
            *(bf16x8*)&b_lds[col * 2 * K + ((CH + sh) << 3)] = al;
        }
        if (RBF) for (int i = tid; i < 8 * 128; i += 256) w2_lds[i] = w_rbf2[i];
    }
    __syncthreads();

    const int lane  = tid & 63;
    const int wid   = tid >> 6;
    const int row   = (blockIdx.x * 4 + wid) * 16;
    const int acol  = lane & 15;
    const int khalf = lane >> 4;

    f32x4 acc[NF];
    #pragma unroll
    for (int n = 0; n < NF; ++n)
        #pragma unroll
        for (int i = 0; i < 4; ++i) acc[n][i] = 0.f;

    const int arow = row + acol;
    const bool aval = arow < E;
    const float* xrow = X + (size_t)arow * K;

    #pragma unroll
    for (int ks = 0; ks < KS; ++ks) {
        const int k0 = ks * 32 + khalf * 8;
        float v[8];
        if (aval) {
            *(float4*)&v[0] = *(const float4*)&xrow[k0];
            *(float4*)&v[4] = *(const float4*)&xrow[k0 + 4];
        } else {
            #pragma unroll
            for (int jj = 0; jj < 8; ++jj) v[jj] = 0.f;
        }
        bf16x8 ah, al;
        #pragma unroll
        for (int jj = 0; jj < 8; ++jj) {
            short h = f2bf(v[jj]);
            ah[jj] = h;
            al[jj] = f2bf(v[jj] - bf2f(h));
        }
        const int sh = (k0 >> 3) ^ (acol & SM);
        #pragma unroll
        for (int n = 0; n < NF; ++n) {
            const int col = n * 16 + acol;
            const bf16x8 bh = *(const bf16x8*)&b_lds[col * 2 * K + (sh << 3)];
            const bf16x8 bl = *(const bf16x8*)&b_lds[col * 2 * K + ((CH + sh) << 3)];
            acc[n] = __builtin_amdgcn_mfma_f32_16x16x32_bf16(ah, bh, acc[n], 0, 0, 0);
            acc[n] = __builtin_amdgcn_mfma_f32_16x16x32_bf16(al, bh, acc[n], 0, 0, 0);
            acc[n] = __builtin_amdgcn_mfma_f32_16x16x32_bf16(ah, bl, acc[n], 0, 0, 0);
        }
    }

    // ---- epilogue ----
    float bvv[NF];
    if (HAS_BIAS) {
        #pragma unroll
        for (int n = 0; n < NF; ++n) bvv[n] = bias[n * 16 + acol];
    }
    float e1r[4][8];
    if (RBF) {
        #pragma unroll
        for (int r = 0; r < 4; ++r) {
            const int ge = row + khalf * 4 + r;
            if (ge < E) {
                *(float4*)&e1r[r][0] = *(const float4*)&re1[(size_t)ge * 8];
                *(float4*)&e1r[r][4] = *(const float4*)&re1[(size_t)ge * 8 + 4];
            }
        }
    }
    #pragma unroll
    for (int n = 0; n < NF; ++n) {
        const int col = n * 16 + acol;
        float w2c[8];
        if (RBF) {
            #pragma unroll
            for (int p = 0; p < 8; ++p) w2c[p] = w2_lds[p * 128 + col];
        }
        #pragma unroll
        for (int r = 0; r < 4; ++r) {
            const int ge = row + khalf * 4 + r;
            if (ge < E) {
                float v = acc[n][r] + (HAS_BIAS ? bvv[n] : 0.f);
                v = silu_f(v);
                if (RBF) {
                    float s = 0.f;
                    #pragma unroll
                    for (int p = 0; p < 8; ++p) s = fmaf(e1r[r][p], w2c[p], s);
                    v *= s;
                }
                if (ADD_Z) v += Z[(size_t)ge * N + col];
                Out[(size_t)ge * N + col] = v;
            }
        }
    }
}

// ---------------- CSR construction (unchanged) ------------------------------

__global__ void count_kernel(const int* __restrict__ idx_ji, int* __restrict__ cnt, int T) {
    const int t = blockIdx.x * 256 + threadIdx.x;
    if (t < T) atomicAdd(&cnt[idx_ji[t]], 1);
}

__global__ void scan_partial_kernel(const int* __restrict__ cnt, int* __restrict__ partial, int E) {
    __shared__ int red[256];
    const int tid = threadIdx.x;
    const int base = blockIdx.x * 1024 + tid * 4;
    int s = 0;
    #pragma unroll
    for (int i = 0; i < 4; ++i) {
        const int g = base + i;
        if (g < E) s += cnt[g];
    }
    red[tid] = s;
    __syncthreads();
    for (int off = 128; off > 0; off >>= 1) {
        if (tid < off) red[tid] += red[tid + off];
        __syncthreads();
    }
    if (tid == 0) partial[blockIdx.x] = red[0];
}

__global__ void scan_block_kernel(const int* __restrict__ partial, int* __restrict__ blockoff,
                                  int NB, int* offsets, int E) {
    __shared__ int red[256];
    const int tid = threadIdx.x;
    int v[4]; int s = 0;
    #pragma unroll
    for (int i = 0; i < 4; ++i) {
        const int g = tid * 4 + i;
        v[i] = (g < NB) ? partial[g] : 0;
        s += v[i];
    }
    red[tid] = s;
    __syncthreads();
    for (int off = 1; off < 256; off <<= 1) {
        const int add = (tid >= off) ? red[tid - off] : 0;
        __syncthreads();
        red[tid] += add;
        __syncthreads();
    }
    int excl = (tid == 0) ? 0 : red[tid - 1];
    #pragma unroll
    for (int i = 0; i < 4; ++i) {
        const int g = tid * 4 + i;
        if (g < NB) blockoff[g] = excl;
        excl += v[i];
    }
    if (tid == 255) offsets[E] = red[255];
}

__global__ void scan_final_kernel(const int* cnt, const int* __restrict__ blockoff,
                                  int* offsets, int* cursor, int E) {
    __shared__ int red[256];
    const int tid = threadIdx.x;
    const int base = blockIdx.x * 1024 + tid * 4;
    int v[4]; int s = 0;
    #pragma unroll
    for (int i = 0; i < 4; ++i) {
        const int g = base + i;
        v[i] = (g < E) ? cnt[g] : 0;
        s += v[i];
    }
    red[tid] = s;
    __syncthreads();
    for (int off = 1; off < 256; off <<= 1) {
        const int add = (tid >= off) ? red[tid - off] : 0;
        __syncthreads();
        red[tid] += add;
        __syncthreads();
    }
    int run = blockoff[blockIdx.x] + ((tid == 0) ? 0 : red[tid - 1]);
    #pragma unroll
    for (int i = 0; i < 4; ++i) {
        const int g = base + i;
        if (g < E) { offsets[g] = run; cursor[g] = run; }
        run += v[i];
    }
}

__global__ void fill_kernel(const int* __restrict__ idx_ji, int* __restrict__ cursor,
                            int* __restrict__ csr, int T) {
    const int t = blockIdx.x * 256 + threadIdx.x;
    if (t < T) {
        const int pos = atomicAdd(&cursor[idx_ji[t]], 1);
        csr[pos] = t;
    }
}

// ---------------- gather: wcol in VGPRs, pipelined chain --------------------
__launch_bounds__(256, 4)
__global__ void gather_kernel(const float* __restrict__ sbf,     // [T, 42]
                              const int* __restrict__ idx_kj,
                              const float* __restrict__ w_sbf1,  // [42, 8]
                              const float* __restrict__ w_sbf2,  // [8, 64]
                              const int* __restrict__ offsets,   // [E+1]
                              const int* __restrict__ csr,       // [T]
                              const float* __restrict__ xkjd,    // [E, 64]
                              float* __restrict__ agg,           // [E, 64]
                              int E)
{
    const int tid  = threadIdx.x;
    const int lane = tid & 63;
    const int e    = blockIdx.x * 4 + (tid >> 6);

    // wcol[q] = (w_sbf1 @ w_sbf2)[q][lane], born in VGPRs and pinned there.
    float w2[8];
    #pragma unroll
    for (int p = 0; p < 8; ++p) w2[p] = w_sbf2[p * 64 + lane];
    float wcol[42];
    #pragma unroll
    for (int q = 0; q < 42; ++q) {
        float s = 0.f;
        #pragma unroll
        for (int p = 0; p < 8; ++p) s = fmaf(w_sbf1[q * 8 + p], w2[p], s);
        wcol[q] = s;
        asm volatile("" : "+v"(wcol[q]));   // keep resident in a VGPR
    }

    if (e >= E) return;
    int j0 = __builtin_amdgcn_readfirstlane(offsets[e]);
    int j1 = __builtin_amdgcn_readfirstlane(offsets[e + 1]);

    float acc = 0.f;
    if (j0 < j1) {
        int t  = __builtin_amdgcn_readfirstlane(csr[j0]);
        int kj = __builtin_amdgcn_readfirstlane(idx_kj[t]);
        for (int j = j0; j < j1; ++j) {
            const float* srow = sbf + (size_t)t * 42;
            const float xv = xkjd[(size_t)kj * 64 + lane];   // issue early
            int tn = 0, kn = 0;
            if (j + 1 < j1) {                                 // prefetch next indices
                tn = __builtin_amdgcn_readfirstlane(csr[j + 1]);
                kn = __builtin_amdgcn_readfirstlane(idx_kj[tn]);
            }
            float s0 = 0.f, s1 = 0.f, s2 = 0.f, s3 = 0.f;     // 4 indep chains
            #pragma unroll
            for (int q = 0; q < 40; q += 4) {
                s0 = fmaf(srow[q + 0], wcol[q + 0], s0);
                s1 = fmaf(srow[q + 1], wcol[q + 1], s1);
                s2 = fmaf(srow[q + 2], wcol[q + 2], s2);
                s3 = fmaf(srow[q + 3], wcol[q + 3], s3);
            }
            s0 = fmaf(srow[40], wcol[40], s0);
            s1 = fmaf(srow[41], wcol[41], s1);
            const float sv = (s0 + s1) + (s2 + s3);
            acc = fmaf(xv, sv, acc);
            t = tn; kj = kn;
        }
    }
    agg[(size_t)e * 64 + lane] = acc;
}

// ---------------------------------------------------------------------------

extern "C" void kernel_launch(void* const* d_in, const int* in_sizes, int n_in,
                              void* d_out, int out_size, void* d_ws, size_t ws_size,
                              hipStream_t stream)
{
    const float* x      = (const float*)d_in[0];
    const float* rbf    = (const float*)d_in[1];
    const float* sbf    = (const float*)d_in[2];
    const int*   idx_kj = (const int*)d_in[3];
    const int*   idx_ji = (const int*)d_in[4];
    const float* w_rbf1 = (const float*)d_in[5];
    const float* w_rbf2 = (const float*)d_in[6];
    const float* w_sbf1 = (const float*)d_in[7];
    const float* w_sbf2 = (const float*)d_in[8];
    const float* w_kj   = (const float*)d_in[9];
    const float* b_kj   = (const float*)d_in[10];
    const float* w_ji   = (const float*)d_in[11];
    const float* b_ji   = (const float*)d_in[12];
    const float* w_down = (const float*)d_in[13];
    const float* w_up   = (const float*)d_in[14];
    const float* r1w1   = (const float*)d_in[15];
    const float* r1b1   = (const float*)d_in[16];
    const float* r1w2   = (const float*)d_in[17];
    const float* r1b2   = (const float*)d_in[18];
    const float* w_bs   = (const float*)d_in[19];
    const float* b_bs   = (const float*)d_in[20];
    const float* r2w1   = (const float*)d_in[21];
    const float* r2b1   = (const float*)d_in[22];
    const float* r2w2   = (const float*)d_in[23];
    const float* r2b2   = (const float*)d_in[24];
    const float* r3w1   = (const float*)d_in[25];
    const float* r3b1   = (const float*)d_in[26];
    const float* r3w2   = (const float*)d_in[27];
    const float* r3b2   = (const float*)d_in[28];

    const int E = in_sizes[0] / 128;
    const int T = in_sizes[2] / 42;

    float* OUT = (float*)d_out;
    float* W1  = (float*)d_ws;                                        // [E,128]
    float* W3  = (float*)((char*)d_ws + (size_t)E * 128 * 4);         // [E,64]
    float* W4  = (float*)((char*)d_ws + (size_t)E * 128 * 4
                                      + (size_t)E * 64 * 4);          // [E,64]

    // CSR scratch + re1 overlaid on W1 (dead until step 5):
    int* cnt      = (int*)W1;                    // [E]
    int* offsets  = cnt + (E + 64);              // [E+1]
    int* partial  = offsets + (E + 64);          // [<=1024]
    int* blockoff = partial + 1024;              // [<=1024]
    int* csr      = blockoff + 1024;             // [T]   (ends ~14.4 MB)
    float* re1    = (float*)((char*)d_ws + (16u << 20));  // [E,8] (dead after step 1)

    const dim3 blk(256);
    const int gM  = (E + 63) / 64;       // MFMA GEMM tiles (64 rows)
    const int gT  = (T + 255) / 256;
    const int NB  = (E + 1023) / 1024;
    const int gE4 = (E + 3) / 4;
    const int gR  = (E * 8 + 255) / 256;

    // 0. re1 = rbf @ w_rbf1
    rbf1_kernel<<<gR, blk, 0, stream>>>(rbf, w_rbf1, re1, E);
    // 1. OUT = silu(x@w_kj + b_kj) * (re1 @ w_rbf2)
    gemm_mfma_kernel<128,128,true,true,false><<<gM, blk, 0, stream>>>(
        x, w_kj, b_kj, nullptr, re1, w_rbf2, OUT, E);
    // 2. W3 = silu(OUT @ w_down)
    gemm_mfma_kernel<128,64,false,false,false><<<gM, blk, 0, stream>>>(
        OUT, w_down, nullptr, nullptr, nullptr, nullptr, W3, E);

    // 3. CSR build
    hipMemsetAsync(cnt, 0, (size_t)E * 4, stream);
    count_kernel<<<gT, blk, 0, stream>>>(idx_ji, cnt, T);
    scan_partial_kernel<<<NB, blk, 0, stream>>>(cnt, partial, E);
    scan_block_kernel<<<1, blk, 0, stream>>>(partial, blockoff, NB, offsets, E);
    scan_final_kernel<<<NB, blk, 0, stream>>>(cnt, blockoff, offsets, cnt, E);
    fill_kernel<<<gT, blk, 0, stream>>>(idx_ji, cnt, csr, T);

    // 4. gather-accumulate
    gather_kernel<<<gE4, blk, 0, stream>>>(
        sbf, idx_kj, w_sbf1, w_sbf2, offsets, csr, W3, W4, E);

    // 5. W1 = silu(x@w_ji + b_ji)
    gemm_mfma_kernel<128,128,true,false,false><<<gM, blk, 0, stream>>>(
        x, w_ji, b_ji, nullptr, nullptr, nullptr, W1, E);
    // 6. W1 = silu(W4 @ w_up) + W1
    gemm_mfma_kernel<64,128,false,false,true><<<gM, blk, 0, stream>>>(
        W4, w_up, nullptr, W1, nullptr, nullptr, W1, E);
    // 7. OUT = silu(W1@r1w1 + r1b1)
    gemm_mfma_kernel<128,128,true,false,false><<<gM, blk, 0, stream>>>(
        W1, r1w1, r1b1, nullptr, nullptr, nullptr, OUT, E);
    // 8. W1 = W1 + silu(OUT@r1w2 + r1b2)
    gemm_mfma_kernel<128,128,true,false,true><<<gM, blk, 0, stream>>>(
        OUT, r1w2, r1b2, W1, nullptr, nullptr, W1, E);
    // 9. OUT = silu(W1@w_bs + b_bs) + x
    gemm_mfma_kernel<128,128,true,false,true><<<gM, blk, 0, stream>>>(
        W1, w_bs, b_bs, x, nullptr, nullptr, OUT, E);
    // 10. W1 = silu(OUT@r2w1 + r2b1)
    gemm_mfma_kernel<128,128,true,false,false><<<gM, blk, 0, stream>>>(
        OUT, r2w1, r2b1, nullptr, nullptr, nullptr, W1, E);
    // 11. OUT = OUT + silu(W1@r2w2 + r2b2)
    gemm_mfma_kernel<128,128,true,false,true><<<gM, blk, 0, stream>>>(
        W1, r2w2, r2b2, OUT, nullptr, nullptr, OUT, E);
    // 12. W1 = silu(OUT@r3w1 + r3b1)
    gemm_mfma_kernel<128,128,true,false,false><<<gM, blk, 0, stream>>>(
        OUT, r3w1, r3b1, nullptr, nullptr, nullptr, W1, E);
    // 13. OUT = OUT + silu(W1@r3w2 + r3b2)
    gemm_mfma_kernel<128,128,true,false,true><<<gM, blk, 0, stream>>>(
        W1, r3w2, r3b2, OUT, nullptr, nullptr, OUT, E);
}

// Round 4
// 2314.572 us; speedup vs baseline: 5.4635x; 1.2760x over previous
//
#include <hip/hip_runtime.h>

// ---------------------------------------------------------------------------
// DimeNet++ interaction block, round 4:
//   - triplet path: E1 = sbf@w_sbf1 precomputed [T,8]; gather does 8-FMA dot
//   - GEMM: 32 rows/wave (128/block), explicit X prefetch, split-bf16 MFMA
// ---------------------------------------------------------------------------

__device__ __forceinline__ float silu_f(float v) {
    return v / (1.0f + __expf(-v));
}

__device__ __forceinline__ short f2bf(float f) {          // RNE float->bf16 bits
    unsigned u = __float_as_uint(f);
    unsigned r = u + 0x7fff + ((u >> 16) & 1);
    return (short)(r >> 16);
}
__device__ __forceinline__ float bf2f(short s) {
    return __uint_as_float(((unsigned)(unsigned short)s) << 16);
}

typedef __attribute__((ext_vector_type(8))) short bf16x8;
typedef __attribute__((ext_vector_type(4))) float f32x4;

// re1[e][p] = sum_q rbf[e][q] * w_rbf1[q][p]
__global__ void rbf1_kernel(const float* __restrict__ rbf, const float* __restrict__ w_rbf1,
                            float* __restrict__ re1, int E) {
    const int i = blockIdx.x * 256 + threadIdx.x;
    const int e = i >> 3, p = i & 7;
    if (e < E) {
        float s = 0.f;
        #pragma unroll
        for (int q = 0; q < 6; ++q) s = fmaf(rbf[e * 6 + q], w_rbf1[q * 8 + p], s);
        re1[i] = s;
    }
}

// E1[t][p] = sum_q sbf[t][q] * w_sbf1[q][p]   (one thread per triplet)
__launch_bounds__(256, 4)
__global__ void e1_kernel(const float* __restrict__ sbf, const float* __restrict__ w_sbf1,
                          float* __restrict__ E1, int T) {
    const int t = blockIdx.x * 256 + threadIdx.x;
    if (t >= T) return;
    const float* srow = sbf + (size_t)t * 42;
    float e1[8] = {0.f, 0.f, 0.f, 0.f, 0.f, 0.f, 0.f, 0.f};
    #pragma unroll
    for (int q = 0; q < 42; q += 2) {
        const float2 sv = *(const float2*)&srow[q];
        #pragma unroll
        for (int p = 0; p < 8; ++p) {
            e1[p] = fmaf(sv.x, w_sbf1[q * 8 + p], e1[p]);
            e1[p] = fmaf(sv.y, w_sbf1[(q + 1) * 8 + p], e1[p]);
        }
    }
    *(float4*)&E1[(size_t)t * 8]     = *(float4*)&e1[0];
    *(float4*)&E1[(size_t)t * 8 + 4] = *(float4*)&e1[4];
}

// ---------------- split-bf16 MFMA GEMM + epilogue ---------------------------
// Block: 256 threads = 4 waves; each wave owns 32 rows (two 16-row frags).
template<int K, int N, bool HAS_BIAS, bool RBF, bool ADD_Z>
__launch_bounds__(256, 2)
__global__ void gemm_mfma_kernel(const float* __restrict__ X,     // [E, K]
                                 const float* __restrict__ W,     // [K, N]
                                 const float* __restrict__ bias,  // [N] or null
                                 const float* __restrict__ Z,     // [E, N] or null
                                 const float* __restrict__ re1,   // [E, 8] or null
                                 const float* __restrict__ w_rbf2,// [8, 128] or null
                                 float* __restrict__ Out,         // [E, N]
                                 int E)
{
    constexpr int NF = N / 16;   // n-frags per wave
    constexpr int KS = K / 32;   // k-steps
    constexpr int CH = K / 8;    // 16B chunks per plane-row
    constexpr int SM = CH - 1;   // swizzle mask

    __shared__ __align__(16) short b_lds[N * 2 * K];
    __shared__ float w2_lds[RBF ? 8 * 128 : 1];

    const int tid = threadIdx.x;

    // ---- stage W -> bf16 hi/lo, transposed + swizzled ----
    {
        constexpr int SEG = 256 / N;
        constexpr int KPS = K / SEG;
        const int col = tid % N;
        const int seg = tid / N;
        #pragma unroll
        for (int j = 0; j < KPS; j += 8) {
            const int kb = seg * KPS + j;
            float v[8];
            #pragma unroll
            for (int jj = 0; jj < 8; ++jj) v[jj] = W[(size_t)(kb + jj) * N + col];
            bf16x8 ah, al;
            #pragma unroll
            for (int jj = 0; jj < 8; ++jj) {
                short h = f2bf(v[jj]);
                ah[jj] = h;
                al[jj] = f2bf(v[jj] - bf2f(h));
            }
            const int ch = kb >> 3;
            const int sh = ch ^ (col & SM);
            *(bf16x8*)&b_lds[col * 2 * K + (sh << 3)]        = ah;
            *(bf16x8*)&b_lds[col * 2 * K + ((CH + sh) << 3)] = al;
        }
        if (RBF) for (int i = tid; i < 8 * 128; i += 256) w2_lds[i] = w_rbf2[i];
    }
    __syncthreads();

    const int lane  = tid & 63;
    const int wid   = tid >> 6;
    const int row   = (blockIdx.x * 4 + wid) * 32;
    const int acol  = lane & 15;
    const int khalf = lane >> 4;

    f32x4 acc[2][NF];
    #pragma unroll
    for (int f = 0; f < 2; ++f)
        #pragma unroll
        for (int n = 0; n < NF; ++n)
            #pragma unroll
            for (int i = 0; i < 4; ++i) acc[f][n][i] = 0.f;

    const int arow0 = row + acol;
    const int arow1 = row + 16 + acol;
    const bool av0 = arow0 < E;
    const bool av1 = arow1 < E;
    const float* xr0 = X + (size_t)arow0 * K;
    const float* xr1 = X + (size_t)arow1 * K;

    float v0[8], v1[8], n0[8], n1[8];

    // initial load (ks = 0)
    {
        const int k0 = khalf * 8;
        #pragma unroll
        for (int jj = 0; jj < 8; ++jj) { v0[jj] = 0.f; v1[jj] = 0.f; }
        if (av0) { *(float4*)&v0[0] = *(const float4*)&xr0[k0]; *(float4*)&v0[4] = *(const float4*)&xr0[k0 + 4]; }
        if (av1) { *(float4*)&v1[0] = *(const float4*)&xr1[k0]; *(float4*)&v1[4] = *(const float4*)&xr1[k0 + 4]; }
    }

    #pragma unroll
    for (int ks = 0; ks < KS; ++ks) {
        // prefetch next k-step
        if (ks + 1 < KS) {
            const int kn = (ks + 1) * 32 + khalf * 8;
            #pragma unroll
            for (int jj = 0; jj < 8; ++jj) { n0[jj] = 0.f; n1[jj] = 0.f; }
            if (av0) { *(float4*)&n0[0] = *(const float4*)&xr0[kn]; *(float4*)&n0[4] = *(const float4*)&xr0[kn + 4]; }
            if (av1) { *(float4*)&n1[0] = *(const float4*)&xr1[kn]; *(float4*)&n1[4] = *(const float4*)&xr1[kn + 4]; }
        }
        // convert current
        bf16x8 ah0, al0, ah1, al1;
        #pragma unroll
        for (int jj = 0; jj < 8; ++jj) {
            short h0 = f2bf(v0[jj]);
            ah0[jj] = h0;
            al0[jj] = f2bf(v0[jj] - bf2f(h0));
            short h1 = f2bf(v1[jj]);
            ah1[jj] = h1;
            al1[jj] = f2bf(v1[jj] - bf2f(h1));
        }
        const int k0 = ks * 32 + khalf * 8;
        const int sh = (k0 >> 3) ^ (acol & SM);
        #pragma unroll
        for (int n = 0; n < NF; ++n) {
            const int col = n * 16 + acol;
            const bf16x8 bh = *(const bf16x8*)&b_lds[col * 2 * K + (sh << 3)];
            const bf16x8 bl = *(const bf16x8*)&b_lds[col * 2 * K + ((CH + sh) << 3)];
            acc[0][n] = __builtin_amdgcn_mfma_f32_16x16x32_bf16(ah0, bh, acc[0][n], 0, 0, 0);
            acc[0][n] = __builtin_amdgcn_mfma_f32_16x16x32_bf16(al0, bh, acc[0][n], 0, 0, 0);
            acc[0][n] = __builtin_amdgcn_mfma_f32_16x16x32_bf16(ah0, bl, acc[0][n], 0, 0, 0);
            acc[1][n] = __builtin_amdgcn_mfma_f32_16x16x32_bf16(ah1, bh, acc[1][n], 0, 0, 0);
            acc[1][n] = __builtin_amdgcn_mfma_f32_16x16x32_bf16(al1, bh, acc[1][n], 0, 0, 0);
            acc[1][n] = __builtin_amdgcn_mfma_f32_16x16x32_bf16(ah1, bl, acc[1][n], 0, 0, 0);
        }
        #pragma unroll
        for (int jj = 0; jj < 8; ++jj) { v0[jj] = n0[jj]; v1[jj] = n1[jj]; }
    }

    // ---- epilogue ----
    float bvv[NF];
    if (HAS_BIAS) {
        #pragma unroll
        for (int n = 0; n < NF; ++n) bvv[n] = bias[n * 16 + acol];
    }
    #pragma unroll
    for (int f = 0; f < 2; ++f) {
        float e1r[4][8];
        if (RBF) {
            #pragma unroll
            for (int r = 0; r < 4; ++r) {
                const int ge = row + f * 16 + khalf * 4 + r;
                if (ge < E) {
                    *(float4*)&e1r[r][0] = *(const float4*)&re1[(size_t)ge * 8];
                    *(float4*)&e1r[r][4] = *(const float4*)&re1[(size_t)ge * 8 + 4];
                }
            }
        }
        #pragma unroll
        for (int n = 0; n < NF; ++n) {
            const int col = n * 16 + acol;
            float w2c[8];
            if (RBF) {
                #pragma unroll
                for (int p = 0; p < 8; ++p) w2c[p] = w2_lds[p * 128 + col];
            }
            #pragma unroll
            for (int r = 0; r < 4; ++r) {
                const int ge = row + f * 16 + khalf * 4 + r;
                if (ge < E) {
                    float v = acc[f][n][r] + (HAS_BIAS ? bvv[n] : 0.f);
                    v = silu_f(v);
                    if (RBF) {
                        float s = 0.f;
                        #pragma unroll
                        for (int p = 0; p < 8; ++p) s = fmaf(e1r[r][p], w2c[p], s);
                        v *= s;
                    }
                    if (ADD_Z) v += Z[(size_t)ge * N + col];
                    Out[(size_t)ge * N + col] = v;
                }
            }
        }
    }
}

// ---------------- CSR construction -----------------------------------------

__global__ void count_kernel(const int* __restrict__ idx_ji, int* __restrict__ cnt, int T) {
    const int t = blockIdx.x * 256 + threadIdx.x;
    if (t < T) atomicAdd(&cnt[idx_ji[t]], 1);
}

__global__ void scan_partial_kernel(const int* __restrict__ cnt, int* __restrict__ partial, int E) {
    __shared__ int red[256];
    const int tid = threadIdx.x;
    const int base = blockIdx.x * 1024 + tid * 4;
    int s = 0;
    #pragma unroll
    for (int i = 0; i < 4; ++i) {
        const int g = base + i;
        if (g < E) s += cnt[g];
    }
    red[tid] = s;
    __syncthreads();
    for (int off = 128; off > 0; off >>= 1) {
        if (tid < off) red[tid] += red[tid + off];
        __syncthreads();
    }
    if (tid == 0) partial[blockIdx.x] = red[0];
}

__global__ void scan_block_kernel(const int* __restrict__ partial, int* __restrict__ blockoff,
                                  int NB, int* offsets, int E) {
    __shared__ int red[256];
    const int tid = threadIdx.x;
    int v[4]; int s = 0;
    #pragma unroll
    for (int i = 0; i < 4; ++i) {
        const int g = tid * 4 + i;
        v[i] = (g < NB) ? partial[g] : 0;
        s += v[i];
    }
    red[tid] = s;
    __syncthreads();
    for (int off = 1; off < 256; off <<= 1) {
        const int add = (tid >= off) ? red[tid - off] : 0;
        __syncthreads();
        red[tid] += add;
        __syncthreads();
    }
    int excl = (tid == 0) ? 0 : red[tid - 1];
    #pragma unroll
    for (int i = 0; i < 4; ++i) {
        const int g = tid * 4 + i;
        if (g < NB) blockoff[g] = excl;
        excl += v[i];
    }
    if (tid == 255) offsets[E] = red[255];
}

__global__ void scan_final_kernel(const int* cnt, const int* __restrict__ blockoff,
                                  int* offsets, int* cursor, int E) {
    __shared__ int red[256];
    const int tid = threadIdx.x;
    const int base = blockIdx.x * 1024 + tid * 4;
    int v[4]; int s = 0;
    #pragma unroll
    for (int i = 0; i < 4; ++i) {
        const int g = base + i;
        v[i] = (g < E) ? cnt[g] : 0;
        s += v[i];
    }
    red[tid] = s;
    __syncthreads();
    for (int off = 1; off < 256; off <<= 1) {
        const int add = (tid >= off) ? red[tid - off] : 0;
        __syncthreads();
        red[tid] += add;
        __syncthreads();
    }
    int run = blockoff[blockIdx.x] + ((tid == 0) ? 0 : red[tid - 1]);
    #pragma unroll
    for (int i = 0; i < 4; ++i) {
        const int g = base + i;
        if (g < E) { offsets[g] = run; cursor[g] = run; }
        run += v[i];
    }
}

__global__ void fill_kernel(const int* __restrict__ idx_ji, int* __restrict__ cursor,
                            int* __restrict__ csr, int T) {
    const int t = blockIdx.x * 256 + threadIdx.x;
    if (t < T) {
        const int pos = atomicAdd(&cursor[idx_ji[t]], 1);
        csr[pos] = t;
    }
}

// ---------------- gather: 8-FMA dot per triplet -----------------------------
__launch_bounds__(256, 4)
__global__ void gather_kernel(const float* __restrict__ E1,      // [T, 8]
                              const int* __restrict__ idx_kj,
                              const float* __restrict__ w_sbf2,  // [8, 64]
                              const int* __restrict__ offsets,   // [E+1]
                              const int* __restrict__ csr,       // [T]
                              const float* __restrict__ xkjd,    // [E, 64]
                              float* __restrict__ agg,           // [E, 64]
                              int E)
{
    const int tid  = threadIdx.x;
    const int lane = tid & 63;
    const int e    = blockIdx.x * 4 + (tid >> 6);

    float w2[8];
    #pragma unroll
    for (int p = 0; p < 8; ++p) w2[p] = w_sbf2[p * 64 + lane];

    if (e >= E) return;
    const int j0 = __builtin_amdgcn_readfirstlane(offsets[e]);
    const int j1 = __builtin_amdgcn_readfirstlane(offsets[e + 1]);

    float acc = 0.f;
    if (j0 < j1) {
        int t  = __builtin_amdgcn_readfirstlane(csr[j0]);
        int kj = __builtin_amdgcn_readfirstlane(idx_kj[t]);
        float4 ea = *(const float4*)&E1[(size_t)t * 8];
        float4 eb = *(const float4*)&E1[(size_t)t * 8 + 4];
        for (int j = j0; j < j1; ++j) {
            const float xv = xkjd[(size_t)kj * 64 + lane];   // issue early
            int kn = 0; float4 ean = {}, ebn = {};
            if (j + 1 < j1) {                                 // prefetch next triplet
                const int tn = __builtin_amdgcn_readfirstlane(csr[j + 1]);
                kn  = __builtin_amdgcn_readfirstlane(idx_kj[tn]);
                ean = *(const float4*)&E1[(size_t)tn * 8];
                ebn = *(const float4*)&E1[(size_t)tn * 8 + 4];
            }
            float sv = ea.x * w2[0];
            sv = fmaf(ea.y, w2[1], sv);
            sv = fmaf(ea.z, w2[2], sv);
            sv = fmaf(ea.w, w2[3], sv);
            sv = fmaf(eb.x, w2[4], sv);
            sv = fmaf(eb.y, w2[5], sv);
            sv = fmaf(eb.z, w2[6], sv);
            sv = fmaf(eb.w, w2[7], sv);
            acc = fmaf(xv, sv, acc);
            kj = kn; ea = ean; eb = ebn;
        }
    }
    agg[(size_t)e * 64 + lane] = acc;
}

// ---------------------------------------------------------------------------

extern "C" void kernel_launch(void* const* d_in, const int* in_sizes, int n_in,
                              void* d_out, int out_size, void* d_ws, size_t ws_size,
                              hipStream_t stream)
{
    const float* x      = (const float*)d_in[0];
    const float* rbf    = (const float*)d_in[1];
    const float* sbf    = (const float*)d_in[2];
    const int*   idx_kj = (const int*)d_in[3];
    const int*   idx_ji = (const int*)d_in[4];
    const float* w_rbf1 = (const float*)d_in[5];
    const float* w_rbf2 = (const float*)d_in[6];
    const float* w_sbf1 = (const float*)d_in[7];
    const float* w_sbf2 = (const float*)d_in[8];
    const float* w_kj   = (const float*)d_in[9];
    const float* b_kj   = (const float*)d_in[10];
    const float* w_ji   = (const float*)d_in[11];
    const float* b_ji   = (const float*)d_in[12];
    const float* w_down = (const float*)d_in[13];
    const float* w_up   = (const float*)d_in[14];
    const float* r1w1   = (const float*)d_in[15];
    const float* r1b1   = (const float*)d_in[16];
    const float* r1w2   = (const float*)d_in[17];
    const float* r1b2   = (const float*)d_in[18];
    const float* w_bs   = (const float*)d_in[19];
    const float* b_bs   = (const float*)d_in[20];
    const float* r2w1   = (const float*)d_in[21];
    const float* r2b1   = (const float*)d_in[22];
    const float* r2w2   = (const float*)d_in[23];
    const float* r2b2   = (const float*)d_in[24];
    const float* r3w1   = (const float*)d_in[25];
    const float* r3b1   = (const float*)d_in[26];
    const float* r3w2   = (const float*)d_in[27];
    const float* r3b2   = (const float*)d_in[28];

    const int E = in_sizes[0] / 128;
    const int T = in_sizes[2] / 42;

    float* OUT = (float*)d_out;
    float* W1  = (float*)d_ws;                                        // [E,128]
    float* W3  = (float*)((char*)d_ws + (size_t)E * 128 * 4);         // [E,64]
    float* W4  = (float*)((char*)d_ws + (size_t)E * 128 * 4
                                      + (size_t)E * 64 * 4);          // [E,64]

    // Overlays inside W1 (dead until step 5):
    //   [0 .. ~14.4MB)  CSR: cnt, offsets, partial, blockoff, csr
    //   [16 .. 25.6MB)  re1 (dead after step 1)
    //   [32 .. 128MB)   E1  (written step 3, read in gather)
    int* cnt      = (int*)W1;                    // [E]
    int* offsets  = cnt + (E + 64);              // [E+1]
    int* partial  = offsets + (E + 64);          // [<=1024]
    int* blockoff = partial + 1024;              // [<=1024]
    int* csr      = blockoff + 1024;             // [T]
    float* re1    = (float*)((char*)d_ws + (16u << 20));   // [E,8]
    float* E1     = (float*)((char*)d_ws + (32u << 20));   // [T,8]

    const dim3 blk(256);
    const int gM  = (E + 127) / 128;     // MFMA GEMM tiles (128 rows/block)
    const int gT  = (T + 255) / 256;
    const int NB  = (E + 1023) / 1024;
    const int gE4 = (E + 3) / 4;
    const int gR  = (E * 8 + 255) / 256;

    // 0. re1 = rbf @ w_rbf1
    rbf1_kernel<<<gR, blk, 0, stream>>>(rbf, w_rbf1, re1, E);
    // 1. OUT = silu(x@w_kj + b_kj) * (re1 @ w_rbf2)
    gemm_mfma_kernel<128,128,true,true,false><<<gM, blk, 0, stream>>>(
        x, w_kj, b_kj, nullptr, re1, w_rbf2, OUT, E);
    // 2. W3 = silu(OUT @ w_down)
    gemm_mfma_kernel<128,64,false,false,false><<<gM, blk, 0, stream>>>(
        OUT, w_down, nullptr, nullptr, nullptr, nullptr, W3, E);
    // 3. E1 = sbf @ w_sbf1
    e1_kernel<<<gT, blk, 0, stream>>>(sbf, w_sbf1, E1, T);

    // 4. CSR build
    hipMemsetAsync(cnt, 0, (size_t)E * 4, stream);
    count_kernel<<<gT, blk, 0, stream>>>(idx_ji, cnt, T);
    scan_partial_kernel<<<NB, blk, 0, stream>>>(cnt, partial, E);
    scan_block_kernel<<<1, blk, 0, stream>>>(partial, blockoff, NB, offsets, E);
    scan_final_kernel<<<NB, blk, 0, stream>>>(cnt, blockoff, offsets, cnt, E);
    fill_kernel<<<gT, blk, 0, stream>>>(idx_ji, cnt, csr, T);

    // 5. gather-accumulate
    gather_kernel<<<gE4, blk, 0, stream>>>(
        E1, idx_kj, w_sbf2, offsets, csr, W3, W4, E);

    // 6. W1 = silu(x@w_ji + b_ji)
    gemm_mfma_kernel<128,128,true,false,false><<<gM, blk, 0, stream>>>(
        x, w_ji, b_ji, nullptr, nullptr, nullptr, W1, E);
    // 7. W1 = silu(W4 @ w_up) + W1
    gemm_mfma_kernel<64,128,false,false,true><<<gM, blk, 0, stream>>>(
        W4, w_up, nullptr, W1, nullptr, nullptr, W1, E);
    // 8. OUT = silu(W1@r1w1 + r1b1)
    gemm_mfma_kernel<128,128,true,false,false><<<gM, blk, 0, stream>>>(
        W1, r1w1, r1b1, nullptr, nullptr, nullptr, OUT, E);
    // 9. W1 = W1 + silu(OUT@r1w2 + r1b2)
    gemm_mfma_kernel<128,128,true,false,true><<<gM, blk, 0, stream>>>(
        OUT, r1w2, r1b2, W1, nullptr, nullptr, W1, E);
    // 10. OUT = silu(W1@w_bs + b_bs) + x
    gemm_mfma_kernel<128,128,true,false,true><<<gM, blk, 0, stream>>>(
        W1, w_bs, b_bs, x, nullptr, nullptr, OUT, E);
    // 11. W1 = silu(OUT@r2w1 + r2b1)
    gemm_mfma_kernel<128,128,true,false,false><<<gM, blk, 0, stream>>>(
        OUT, r2w1, r2b1, nullptr, nullptr, nullptr, W1, E);
    // 12. OUT = OUT + silu(W1@r2w2 + r2b2)
    gemm_mfma_kernel<128,128,true,false,true><<<gM, blk, 0, stream>>>(
        W1, r2w2, r2b2, OUT, nullptr, nullptr, OUT, E);
    // 13. W1 = silu(OUT@r3w1 + r3b1)
    gemm_mfma_kernel<128,128,true,false,false><<<gM, blk, 0, stream>>>(
        OUT, r3w1, r3b1, nullptr, nullptr, nullptr, W1, E);
    // 14. OUT = OUT + silu(W1@r3w2 + r3b2)
    gemm_mfma_kernel<128,128,true,false,true><<<gM, blk, 0, stream>>>(
        W1, r3w2, r3b2, OUT, nullptr, nullptr, OUT, E);
}

// Round 5
// 1631.774 us; speedup vs baseline: 7.7496x; 1.4184x over previous
//
#include <hip/hip_runtime.h>

// ---------------------------------------------------------------------------
// DimeNet++ interaction block, round 5: fused GEMM chains + permuted E1 stream.
//   E = 300000, T = 3000000, D = 128, D_DOWN = 64.
// Pipeline:
//   rbf1:   re1 = rbf@w_rbf1                                   [E,8]
//   count/scan: CSR offsets of idx_ji
//   e1fill: per triplet t: e1 = sbf[t]@w_sbf1; pos=cursor[ji]++;
//           E1p[pos]=e1; kjp[pos]=idx_kj[t]
//   K1:     W3 = silu( (silu(x@w_kj+b_kj) * (re1@w_rbf2)) @ w_down )   (fused)
//   gather: W4[e] = sum_j (E1p[j]·w2col) * W3[kjp[j]]          (sequential)
//   K4:     h0 = silu(x@w_ji+b_ji) + silu(W4@w_up)             (fused)
//   K5:     OUT = silu(res1(h0)@w_bs+b_bs) + x                 (3 GEMMs fused)
//   K6/K7:  OUT = OUT + silu(silu(OUT@w1+b1)@w2+b2)            (in-place, fused)
// All GEMMs: split-bf16 hi/lo 3-pass MFMA (fp32 quality); inner activations
// bounce through a fp32 LDS tile (never written to HBM).
// ---------------------------------------------------------------------------

typedef __attribute__((ext_vector_type(8))) short bf16x8;
typedef __attribute__((ext_vector_type(4))) float f32x4;

__device__ __forceinline__ float silu_f(float v) { return v / (1.0f + __expf(-v)); }
__device__ __forceinline__ short f2bf(float f) {
    unsigned u = __float_as_uint(f);
    unsigned r = u + 0x7fffu + ((u >> 16) & 1u);
    return (short)(r >> 16);
}
__device__ __forceinline__ float bf2f(short s) {
    return __uint_as_float(((unsigned)(unsigned short)s) << 16);
}
__device__ __forceinline__ void split8(const float* v, bf16x8& ah, bf16x8& al) {
    #pragma unroll
    for (int j = 0; j < 8; ++j) { short h = f2bf(v[j]); ah[j] = h; al[j] = f2bf(v[j] - bf2f(h)); }
}

// stage W[K][N] fp32 -> wslot bf16 hi/lo, transposed + chunk-swizzled (512 thr)
template<int K, int N>
__device__ __forceinline__ void stage_w(const float* __restrict__ W, short* wslot, int tid) {
    constexpr int SEG = 512 / N, KPS = K / SEG, SM = K / 8 - 1, CH = K / 8;
    const int col = tid % N, seg = tid / N;
    #pragma unroll
    for (int j = 0; j < KPS; j += 8) {
        const int kb = seg * KPS + j;
        float v[8];
        #pragma unroll
        for (int jj = 0; jj < 8; ++jj) v[jj] = W[(size_t)(kb + jj) * N + col];
        bf16x8 ah, al; split8(v, ah, al);
        const int sh = (kb >> 3) ^ (col & SM);
        *(bf16x8*)&wslot[col * 2 * K + (sh << 3)]        = ah;
        *(bf16x8*)&wslot[col * 2 * K + ((CH + sh) << 3)] = al;
    }
}

// one 32-wide k-step, 3-pass split MFMA over NF column-frags
template<int K, int N, int NF>
__device__ __forceinline__ void mfma_step(const bf16x8& ah, const bf16x8& al,
                                          const short* wslot, int k0, int acol, f32x4* acc) {
    constexpr int SM = K / 8 - 1, CH = K / 8;
    const int sh = (k0 >> 3) ^ (acol & SM);
    #pragma unroll
    for (int n = 0; n < NF; ++n) {
        const int col = n * 16 + acol;
        const bf16x8 bh = *(const bf16x8*)&wslot[col * 2 * K + (sh << 3)];
        const bf16x8 bl = *(const bf16x8*)&wslot[col * 2 * K + ((CH + sh) << 3)];
        acc[n] = __builtin_amdgcn_mfma_f32_16x16x32_bf16(ah, bh, acc[n], 0, 0, 0);
        acc[n] = __builtin_amdgcn_mfma_f32_16x16x32_bf16(al, bh, acc[n], 0, 0, 0);
        acc[n] = __builtin_amdgcn_mfma_f32_16x16x32_bf16(ah, bl, acc[n], 0, 0, 0);
    }
}

#define TPITCH 132   // t_lds row pitch in floats (128 + 4 pad; keeps 16B align)

// ---------------- small prologue kernels ------------------------------------

__global__ void rbf1_kernel(const float* __restrict__ rbf, const float* __restrict__ w_rbf1,
                            float* __restrict__ re1, int E) {
    const int i = blockIdx.x * 256 + threadIdx.x;
    const int e = i >> 3, p = i & 7;
    if (e < E) {
        float s = 0.f;
        #pragma unroll
        for (int q = 0; q < 6; ++q) s = fmaf(rbf[e * 6 + q], w_rbf1[q * 8 + p], s);
        re1[i] = s;
    }
}

__global__ void count_kernel(const int* __restrict__ idx_ji, int* __restrict__ cnt, int T) {
    const int t = blockIdx.x * 256 + threadIdx.x;
    if (t < T) atomicAdd(&cnt[idx_ji[t]], 1);
}

__global__ void scan_partial_kernel(const int* __restrict__ cnt, int* __restrict__ partial, int E) {
    __shared__ int red[256];
    const int tid = threadIdx.x;
    const int base = blockIdx.x * 1024 + tid * 4;
    int s = 0;
    #pragma unroll
    for (int i = 0; i < 4; ++i) { const int g = base + i; if (g < E) s += cnt[g]; }
    red[tid] = s;
    __syncthreads();
    for (int off = 128; off > 0; off >>= 1) {
        if (tid < off) red[tid] += red[tid + off];
        __syncthreads();
    }
    if (tid == 0) partial[blockIdx.x] = red[0];
}

__global__ void scan_block_kernel(const int* __restrict__ partial, int* __restrict__ blockoff,
                                  int NB, int* offsets, int E) {
    __shared__ int red[256];
    const int tid = threadIdx.x;
    int v[4]; int s = 0;
    #pragma unroll
    for (int i = 0; i < 4; ++i) { const int g = tid * 4 + i; v[i] = (g < NB) ? partial[g] : 0; s += v[i]; }
    red[tid] = s;
    __syncthreads();
    for (int off = 1; off < 256; off <<= 1) {
        const int add = (tid >= off) ? red[tid - off] : 0;
        __syncthreads();
        red[tid] += add;
        __syncthreads();
    }
    int excl = (tid == 0) ? 0 : red[tid - 1];
    #pragma unroll
    for (int i = 0; i < 4; ++i) { const int g = tid * 4 + i; if (g < NB) blockoff[g] = excl; excl += v[i]; }
    if (tid == 255) offsets[E] = red[255];
}

__global__ void scan_final_kernel(const int* cnt, const int* __restrict__ blockoff,
                                  int* offsets, int* cursor, int E) {
    __shared__ int red[256];
    const int tid = threadIdx.x;
    const int base = blockIdx.x * 1024 + tid * 4;
    int v[4]; int s = 0;
    #pragma unroll
    for (int i = 0; i < 4; ++i) { const int g = base + i; v[i] = (g < E) ? cnt[g] : 0; s += v[i]; }
    red[tid] = s;
    __syncthreads();
    for (int off = 1; off < 256; off <<= 1) {
        const int add = (tid >= off) ? red[tid - off] : 0;
        __syncthreads();
        red[tid] += add;
        __syncthreads();
    }
    int run = blockoff[blockIdx.x] + ((tid == 0) ? 0 : red[tid - 1]);
    #pragma unroll
    for (int i = 0; i < 4; ++i) {
        const int g = base + i;
        if (g < E) { offsets[g] = run; cursor[g] = run; }
        run += v[i];
    }
}

// e1 projection fused with CSR fill: E1p/kjp land at CSR position
__launch_bounds__(256, 4)
__global__ void e1fill_kernel(const float* __restrict__ sbf, const float* __restrict__ w_sbf1,
                              const int* __restrict__ idx_ji, const int* __restrict__ idx_kj,
                              int* __restrict__ cursor,
                              float* __restrict__ E1p, int* __restrict__ kjp, int T) {
    const int t = blockIdx.x * 256 + threadIdx.x;
    if (t >= T) return;
    const float* srow = sbf + (size_t)t * 42;
    float e1[8] = {0.f, 0.f, 0.f, 0.f, 0.f, 0.f, 0.f, 0.f};
    #pragma unroll
    for (int q = 0; q < 42; q += 2) {
        const float2 sv = *(const float2*)&srow[q];
        #pragma unroll
        for (int p = 0; p < 8; ++p) {
            e1[p] = fmaf(sv.x, w_sbf1[q * 8 + p], e1[p]);
            e1[p] = fmaf(sv.y, w_sbf1[(q + 1) * 8 + p], e1[p]);
        }
    }
    const int pos = atomicAdd(&cursor[idx_ji[t]], 1);
    *(float4*)&E1p[(size_t)pos * 8]     = *(float4*)&e1[0];
    *(float4*)&E1p[(size_t)pos * 8 + 4] = *(float4*)&e1[4];
    kjp[pos] = idx_kj[t];
}

// ---------------- gather: sequential E1p/kjp streams -------------------------
__launch_bounds__(256, 4)
__global__ void gather_kernel(const float* __restrict__ E1p,     // [T, 8] permuted
                              const int* __restrict__ kjp,       // [T]    permuted
                              const float* __restrict__ w_sbf2,  // [8, 64]
                              const int* __restrict__ offsets,   // [E+1]
                              const float* __restrict__ xkjd,    // [E, 64]
                              float* __restrict__ agg,           // [E, 64]
                              int E)
{
    const int tid  = threadIdx.x;
    const int lane = tid & 63;
    const int e    = blockIdx.x * 4 + (tid >> 6);

    float w2[8];
    #pragma unroll
    for (int p = 0; p < 8; ++p) w2[p] = w_sbf2[p * 64 + lane];

    if (e >= E) return;
    const int j0 = __builtin_amdgcn_readfirstlane(offsets[e]);
    const int j1 = __builtin_amdgcn_readfirstlane(offsets[e + 1]);

    float acc = 0.f;
    if (j0 < j1) {
        int kj = __builtin_amdgcn_readfirstlane(kjp[j0]);
        float4 ea = *(const float4*)&E1p[(size_t)j0 * 8];
        float4 eb = *(const float4*)&E1p[(size_t)j0 * 8 + 4];
        for (int j = j0; j < j1; ++j) {
            const float xv = xkjd[(size_t)kj * 64 + lane];   // issue early
            int kn = 0; float4 ean = {}, ebn = {};
            if (j + 1 < j1) {
                kn  = __builtin_amdgcn_readfirstlane(kjp[j + 1]);
                ean = *(const float4*)&E1p[(size_t)(j + 1) * 8];
                ebn = *(const float4*)&E1p[(size_t)(j + 1) * 8 + 4];
            }
            float sv = ea.x * w2[0];
            sv = fmaf(ea.y, w2[1], sv);
            sv = fmaf(ea.z, w2[2], sv);
            sv = fmaf(ea.w, w2[3], sv);
            sv = fmaf(eb.x, w2[4], sv);
            sv = fmaf(eb.y, w2[5], sv);
            sv = fmaf(eb.z, w2[6], sv);
            sv = fmaf(eb.w, w2[7], sv);
            acc = fmaf(xv, sv, acc);
            kj = kn; ea = ean; eb = ebn;
        }
    }
    agg[(size_t)e * 64 + lane] = acc;
}

// ---------------- K1: W3 = silu((silu(x@w_kj+b)*rbf_e)@w_down) --------------
__launch_bounds__(512, 1)
__global__ void k1_kernel(const float* __restrict__ x, const float* __restrict__ w_kj,
                          const float* __restrict__ b_kj, const float* __restrict__ re1,
                          const float* __restrict__ w_rbf2, const float* __restrict__ w_down,
                          float* __restrict__ W3, int E)
{
    __shared__ __align__(16) short wslot[128 * 2 * 128];
    __shared__ __align__(16) float t_lds[128 * TPITCH];
    __shared__ float w2_lds[8 * 128];
    const int tid = threadIdx.x, lane = tid & 63, wid = tid >> 6;
    const int row0 = blockIdx.x * 128 + wid * 16;
    const int acol = lane & 15, kq = lane >> 4;

    const int arow = row0 + acol;
    const bool av = arow < E;
    const float* xr = x + (size_t)arow * 128;
    float va[4][8];
    #pragma unroll
    for (int ks = 0; ks < 4; ++ks) {
        #pragma unroll
        for (int jj = 0; jj < 8; ++jj) va[ks][jj] = 0.f;
        if (av) {
            const int k0 = ks * 32 + kq * 8;
            *(float4*)&va[ks][0] = *(const float4*)&xr[k0];
            *(float4*)&va[ks][4] = *(const float4*)&xr[k0 + 4];
        }
    }
    stage_w<128, 128>(w_kj, wslot, tid);
    for (int i = tid; i < 1024; i += 512) w2_lds[i] = w_rbf2[i];
    __syncthreads();

    f32x4 acc[8];
    #pragma unroll
    for (int n = 0; n < 8; ++n)
        #pragma unroll
        for (int i = 0; i < 4; ++i) acc[n][i] = 0.f;
    #pragma unroll
    for (int ks = 0; ks < 4; ++ks) {
        bf16x8 ah, al; split8(va[ks], ah, al);
        mfma_step<128, 128, 8>(ah, al, wslot, ks * 32 + kq * 8, acol, acc);
    }

    // epilogue 1: u = silu(acc+b)*rbf_e -> t_lds
    float e1r[4][8];
    #pragma unroll
    for (int r = 0; r < 4; ++r) {
        const int ge = row0 + kq * 4 + r;
        if (ge < E) {
            *(float4*)&e1r[r][0] = *(const float4*)&re1[(size_t)ge * 8];
            *(float4*)&e1r[r][4] = *(const float4*)&re1[(size_t)ge * 8 + 4];
        } else {
            #pragma unroll
            for (int p = 0; p < 8; ++p) e1r[r][p] = 0.f;
        }
    }
    #pragma unroll
    for (int n = 0; n < 8; ++n) {
        const int col = n * 16 + acol;
        const float bv = b_kj[col];
        float w2c[8];
        #pragma unroll
        for (int p = 0; p < 8; ++p) w2c[p] = w2_lds[p * 128 + col];
        #pragma unroll
        for (int r = 0; r < 4; ++r) {
            float s = 0.f;
            #pragma unroll
            for (int p = 0; p < 8; ++p) s = fmaf(e1r[r][p], w2c[p], s);
            t_lds[(wid * 16 + kq * 4 + r) * TPITCH + col] = silu_f(acc[n][r] + bv) * s;
        }
    }
    __syncthreads();                    // wslot reads + t writes complete
    stage_w<128, 64>(w_down, wslot, tid);
    __syncthreads();

    f32x4 acc2[4];
    #pragma unroll
    for (int n = 0; n < 4; ++n)
        #pragma unroll
        for (int i = 0; i < 4; ++i) acc2[n][i] = 0.f;
    const float* trow = &t_lds[(wid * 16 + acol) * TPITCH];
    #pragma unroll
    for (int ks = 0; ks < 4; ++ks) {
        float v[8];
        const int k0 = ks * 32 + kq * 8;
        *(float4*)&v[0] = *(const float4*)&trow[k0];
        *(float4*)&v[4] = *(const float4*)&trow[k0 + 4];
        bf16x8 ah, al; split8(v, ah, al);
        mfma_step<128, 64, 4>(ah, al, wslot, k0, acol, acc2);
    }
    #pragma unroll
    for (int n = 0; n < 4; ++n) {
        const int col = n * 16 + acol;
        #pragma unroll
        for (int r = 0; r < 4; ++r) {
            const int ge = row0 + kq * 4 + r;
            if (ge < E) W3[(size_t)ge * 64 + col] = silu_f(acc2[n][r]);
        }
    }
}

// ---------------- K4: h0 = silu(x@w_ji+b_ji) + silu(W4@w_up) ----------------
__launch_bounds__(512, 1)
__global__ void k4_kernel(const float* __restrict__ x, const float* __restrict__ w_ji,
                          const float* __restrict__ b_ji, const float* __restrict__ W4,
                          const float* __restrict__ w_up, float* __restrict__ h0, int E)
{
    __shared__ __align__(16) short wslot[128 * 2 * 128];
    const int tid = threadIdx.x, lane = tid & 63, wid = tid >> 6;
    const int row0 = blockIdx.x * 128 + wid * 16;
    const int acol = lane & 15, kq = lane >> 4;

    const int arow = row0 + acol;
    const bool av = arow < E;
    const float* xr = x + (size_t)arow * 128;
    const float* wr = W4 + (size_t)arow * 64;
    float va[4][8], vb[2][8];
    #pragma unroll
    for (int ks = 0; ks < 4; ++ks) {
        #pragma unroll
        for (int jj = 0; jj < 8; ++jj) va[ks][jj] = 0.f;
        if (av) {
            const int k0 = ks * 32 + kq * 8;
            *(float4*)&va[ks][0] = *(const float4*)&xr[k0];
            *(float4*)&va[ks][4] = *(const float4*)&xr[k0 + 4];
        }
    }
    #pragma unroll
    for (int ks = 0; ks < 2; ++ks) {
        #pragma unroll
        for (int jj = 0; jj < 8; ++jj) vb[ks][jj] = 0.f;
        if (av) {
            const int k0 = ks * 32 + kq * 8;
            *(float4*)&vb[ks][0] = *(const float4*)&wr[k0];
            *(float4*)&vb[ks][4] = *(const float4*)&wr[k0 + 4];
        }
    }
    stage_w<128, 128>(w_ji, wslot, tid);
    __syncthreads();

    f32x4 acc1[8], acc2[8];
    #pragma unroll
    for (int n = 0; n < 8; ++n)
        #pragma unroll
        for (int i = 0; i < 4; ++i) { acc1[n][i] = 0.f; acc2[n][i] = 0.f; }
    #pragma unroll
    for (int ks = 0; ks < 4; ++ks) {
        bf16x8 ah, al; split8(va[ks], ah, al);
        mfma_step<128, 128, 8>(ah, al, wslot, ks * 32 + kq * 8, acol, acc1);
    }
    __syncthreads();                    // wslot reads complete
    stage_w<64, 128>(w_up, wslot, tid);
    __syncthreads();
    #pragma unroll
    for (int ks = 0; ks < 2; ++ks) {
        bf16x8 ah, al; split8(vb[ks], ah, al);
        mfma_step<64, 128, 8>(ah, al, wslot, ks * 32 + kq * 8, acol, acc2);
    }
    #pragma unroll
    for (int n = 0; n < 8; ++n) {
        const int col = n * 16 + acol;
        const float bv = b_ji[col];
        #pragma unroll
        for (int r = 0; r < 4; ++r) {
            const int ge = row0 + kq * 4 + r;
            if (ge < E)
                h0[(size_t)ge * 128 + col] = silu_f(acc1[n][r] + bv) + silu_f(acc2[n][r]);
        }
    }
}

// ---------------- K5: OUT = silu(res1(h0)@w_bs+b_bs) + x --------------------
__launch_bounds__(512, 1)
__global__ void k5_kernel(const float* __restrict__ h0, const float* __restrict__ x,
                          const float* __restrict__ w1, const float* __restrict__ b1,
                          const float* __restrict__ w2, const float* __restrict__ b2,
                          const float* __restrict__ wbs, const float* __restrict__ bbs,
                          float* __restrict__ out, int E)
{
    __shared__ __align__(16) short wslot[128 * 2 * 128];
    __shared__ __align__(16) float t_lds[128 * TPITCH];
    const int tid = threadIdx.x, lane = tid & 63, wid = tid >> 6;
    const int row0 = blockIdx.x * 128 + wid * 16;
    const int acol = lane & 15, kq = lane >> 4;

    const int arow = row0 + acol;
    const bool av = arow < E;
    const float* hr = h0 + (size_t)arow * 128;
    float va[4][8];
    #pragma unroll
    for (int ks = 0; ks < 4; ++ks) {
        #pragma unroll
        for (int jj = 0; jj < 8; ++jj) va[ks][jj] = 0.f;
        if (av) {
            const int k0 = ks * 32 + kq * 8;
            *(float4*)&va[ks][0] = *(const float4*)&hr[k0];
            *(float4*)&va[ks][4] = *(const float4*)&hr[k0 + 4];
        }
    }
    stage_w<128, 128>(w1, wslot, tid);
    __syncthreads();

    f32x4 acc[8];
    #pragma unroll
    for (int n = 0; n < 8; ++n)
        #pragma unroll
        for (int i = 0; i < 4; ++i) acc[n][i] = 0.f;
    #pragma unroll
    for (int ks = 0; ks < 4; ++ks) {
        bf16x8 ah, al; split8(va[ks], ah, al);
        mfma_step<128, 128, 8>(ah, al, wslot, ks * 32 + kq * 8, acol, acc);
    }
    #pragma unroll
    for (int n = 0; n < 8; ++n) {
        const int col = n * 16 + acol;
        const float bv = b1[col];
        #pragma unroll
        for (int r = 0; r < 4; ++r)
            t_lds[(wid * 16 + kq * 4 + r) * TPITCH + col] = silu_f(acc[n][r] + bv);
    }
    __syncthreads();
    stage_w<128, 128>(w2, wslot, tid);
    __syncthreads();

    // GEMM2 from t_lds; t2 = h0 + silu(acc2+b2) kept in registers
    f32x4 acc2[8];
    #pragma unroll
    for (int n = 0; n < 8; ++n)
        #pragma unroll
        for (int i = 0; i < 4; ++i) acc2[n][i] = 0.f;
    const float* trow = &t_lds[(wid * 16 + acol) * TPITCH];
    #pragma unroll
    for (int ks = 0; ks < 4; ++ks) {
        float v[8];
        const int k0 = ks * 32 + kq * 8;
        *(float4*)&v[0] = *(const float4*)&trow[k0];
        *(float4*)&v[4] = *(const float4*)&trow[k0 + 4];
        bf16x8 ah, al; split8(v, ah, al);
        mfma_step<128, 128, 8>(ah, al, wslot, k0, acol, acc2);
    }
    float t2[8][4];
    #pragma unroll
    for (int n = 0; n < 8; ++n) {
        const int col = n * 16 + acol;
        const float bv = b2[col];
        #pragma unroll
        for (int r = 0; r < 4; ++r) {
            const int ge = row0 + kq * 4 + r;
            const float hz = (ge < E) ? h0[(size_t)ge * 128 + col] : 0.f;
            t2[n][r] = hz + silu_f(acc2[n][r] + bv);
        }
    }
    __syncthreads();                    // all t1 reads complete
    #pragma unroll
    for (int n = 0; n < 8; ++n) {
        const int col = n * 16 + acol;
        #pragma unroll
        for (int r = 0; r < 4; ++r)
            t_lds[(wid * 16 + kq * 4 + r) * TPITCH + col] = t2[n][r];
    }
    stage_w<128, 128>(wbs, wslot, tid);
    __syncthreads();

    f32x4 acc3[8];
    #pragma unroll
    for (int n = 0; n < 8; ++n)
        #pragma unroll
        for (int i = 0; i < 4; ++i) acc3[n][i] = 0.f;
    #pragma unroll
    for (int ks = 0; ks < 4; ++ks) {
        float v[8];
        const int k0 = ks * 32 + kq * 8;
        *(float4*)&v[0] = *(const float4*)&trow[k0];
        *(float4*)&v[4] = *(const float4*)&trow[k0 + 4];
        bf16x8 ah, al; split8(v, ah, al);
        mfma_step<128, 128, 8>(ah, al, wslot, k0, acol, acc3);
    }
    #pragma unroll
    for (int n = 0; n < 8; ++n) {
        const int col = n * 16 + acol;
        const float bv = bbs[col];
        #pragma unroll
        for (int r = 0; r < 4; ++r) {
            const int ge = row0 + kq * 4 + r;
            if (ge < E)
                out[(size_t)ge * 128 + col] = silu_f(acc3[n][r] + bv) + x[(size_t)ge * 128 + col];
        }
    }
}

// ---------------- res block, in-place: h += silu(silu(h@w1+b1)@w2+b2) -------
__launch_bounds__(512, 1)
__global__ void res_kernel(float* __restrict__ h,
                           const float* __restrict__ w1, const float* __restrict__ b1,
                           const float* __restrict__ w2, const float* __restrict__ b2, int E)
{
    __shared__ __align__(16) short wslot[128 * 2 * 128];
    __shared__ __align__(16) float t_lds[128 * TPITCH];
    const int tid = threadIdx.x, lane = tid & 63, wid = tid >> 6;
    const int row0 = blockIdx.x * 128 + wid * 16;
    const int acol = lane & 15, kq = lane >> 4;

    const int arow = row0 + acol;
    const bool av = arow < E;
    const float* hr = h + (size_t)arow * 128;
    float va[4][8];
    #pragma unroll
    for (int ks = 0; ks < 4; ++ks) {
        #pragma unroll
        for (int jj = 0; jj < 8; ++jj) va[ks][jj] = 0.f;
        if (av) {
            const int k0 = ks * 32 + kq * 8;
            *(float4*)&va[ks][0] = *(const float4*)&hr[k0];
            *(float4*)&va[ks][4] = *(const float4*)&hr[k0 + 4];
        }
    }
    stage_w<128, 128>(w1, wslot, tid);
    __syncthreads();

    f32x4 acc[8];
    #pragma unroll
    for (int n = 0; n < 8; ++n)
        #pragma unroll
        for (int i = 0; i < 4; ++i) acc[n][i] = 0.f;
    #pragma unroll
    for (int ks = 0; ks < 4; ++ks) {
        bf16x8 ah, al; split8(va[ks], ah, al);
        mfma_step<128, 128, 8>(ah, al, wslot, ks * 32 + kq * 8, acol, acc);
    }
    #pragma unroll
    for (int n = 0; n < 8; ++n) {
        const int col = n * 16 + acol;
        const float bv = b1[col];
        #pragma unroll
        for (int r = 0; r < 4; ++r)
            t_lds[(wid * 16 + kq * 4 + r) * TPITCH + col] = silu_f(acc[n][r] + bv);
    }
    __syncthreads();
    stage_w<128, 128>(w2, wslot, tid);
    __syncthreads();

    f32x4 acc2[8];
    #pragma unroll
    for (int n = 0; n < 8; ++n)
        #pragma unroll
        for (int i = 0; i < 4; ++i) acc2[n][i] = 0.f;
    const float* trow = &t_lds[(wid * 16 + acol) * TPITCH];
    #pragma unroll
    for (int ks = 0; ks < 4; ++ks) {
        float v[8];
        const int k0 = ks * 32 + kq * 8;
        *(float4*)&v[0] = *(const float4*)&trow[k0];
        *(float4*)&v[4] = *(const float4*)&trow[k0 + 4];
        bf16x8 ah, al; split8(v, ah, al);
        mfma_step<128, 128, 8>(ah, al, wslot, k0, acol, acc2);
    }
    #pragma unroll
    for (int n = 0; n < 8; ++n) {
        const int col = n * 16 + acol;
        const float bv = b2[col];
        #pragma unroll
        for (int r = 0; r < 4; ++r) {
            const int ge = row0 + kq * 4 + r;
            if (ge < E) {
                const float hz = h[(size_t)ge * 128 + col];
                h[(size_t)ge * 128 + col] = hz + silu_f(acc2[n][r] + bv);
            }
        }
    }
}

// ---------------------------------------------------------------------------

extern "C" void kernel_launch(void* const* d_in, const int* in_sizes, int n_in,
                              void* d_out, int out_size, void* d_ws, size_t ws_size,
                              hipStream_t stream)
{
    const float* x      = (const float*)d_in[0];
    const float* rbf    = (const float*)d_in[1];
    const float* sbf    = (const float*)d_in[2];
    const int*   idx_kj = (const int*)d_in[3];
    const int*   idx_ji = (const int*)d_in[4];
    const float* w_rbf1 = (const float*)d_in[5];
    const float* w_rbf2 = (const float*)d_in[6];
    const float* w_sbf1 = (const float*)d_in[7];
    const float* w_sbf2 = (const float*)d_in[8];
    const float* w_kj   = (const float*)d_in[9];
    const float* b_kj   = (const float*)d_in[10];
    const float* w_ji   = (const float*)d_in[11];
    const float* b_ji   = (const float*)d_in[12];
    const float* w_down = (const float*)d_in[13];
    const float* w_up   = (const float*)d_in[14];
    const float* r1w1   = (const float*)d_in[15];
    const float* r1b1   = (const float*)d_in[16];
    const float* r1w2   = (const float*)d_in[17];
    const float* r1b2   = (const float*)d_in[18];
    const float* w_bs   = (const float*)d_in[19];
    const float* b_bs   = (const float*)d_in[20];
    const float* r2w1   = (const float*)d_in[21];
    const float* r2b1   = (const float*)d_in[22];
    const float* r2w2   = (const float*)d_in[23];
    const float* r2b2   = (const float*)d_in[24];
    const float* r3w1   = (const float*)d_in[25];
    const float* r3b1   = (const float*)d_in[26];
    const float* r3w2   = (const float*)d_in[27];
    const float* r3b2   = (const float*)d_in[28];

    const int E = in_sizes[0] / 128;
    const int T = in_sizes[2] / 42;

    float* OUT = (float*)d_out;
    float* W1  = (float*)d_ws;                                        // [E,128] h0
    float* W3  = (float*)((char*)d_ws + (size_t)E * 128 * 4);         // [E,64]
    float* W4  = (float*)((char*)d_ws + (size_t)E * 128 * 4
                                      + (size_t)E * 64 * 4);          // [E,64]

    // Overlays inside the W1 region (all dead before K4 writes h0):
    int*   cnt      = (int*)W1;                              // [E]  (cursor after scan)
    int*   offsets  = cnt + (E + 64);                        // [E+1]
    int*   partial  = offsets + (E + 64);                    // [<=1024]
    int*   blockoff = partial + 1024;                        // [<=1024]
    float* E1p      = (float*)((char*)d_ws + (4u << 20));    // [T,8]  96MB
    int*   kjp      = (int*)((char*)d_ws + (102u << 20));    // [T]    12MB
    float* re1      = (float*)((char*)d_ws + (116u << 20));  // [E,8]  9.6MB

    const dim3 b256(256), b512(512);
    const int gB  = (E + 127) / 128;     // fused GEMM tiles
    const int gT  = (T + 255) / 256;
    const int NB  = (E + 1023) / 1024;
    const int gE4 = (E + 3) / 4;
    const int gR  = (E * 8 + 255) / 256;

    // prologue + CSR
    rbf1_kernel<<<gR, b256, 0, stream>>>(rbf, w_rbf1, re1, E);
    hipMemsetAsync(cnt, 0, (size_t)E * 4, stream);
    count_kernel<<<gT, b256, 0, stream>>>(idx_ji, cnt, T);
    scan_partial_kernel<<<NB, b256, 0, stream>>>(cnt, partial, E);
    scan_block_kernel<<<1, b256, 0, stream>>>(partial, blockoff, NB, offsets, E);
    scan_final_kernel<<<NB, b256, 0, stream>>>(cnt, blockoff, offsets, cnt, E);
    e1fill_kernel<<<gT, b256, 0, stream>>>(sbf, w_sbf1, idx_ji, idx_kj, cnt, E1p, kjp, T);

    // K1: x -> W3 (fused 2 GEMMs + rbf epilogue)
    k1_kernel<<<gB, b512, 0, stream>>>(x, w_kj, b_kj, re1, w_rbf2, w_down, W3, E);

    // gather: -> W4
    gather_kernel<<<gE4, b256, 0, stream>>>(E1p, kjp, w_sbf2, offsets, W3, W4, E);

    // K4: x, W4 -> h0 (W1)
    k4_kernel<<<gB, b512, 0, stream>>>(x, w_ji, b_ji, W4, w_up, W1, E);

    // K5: h0, x -> OUT (res1 + w_bs + skip, 3 GEMMs fused)
    k5_kernel<<<gB, b512, 0, stream>>>(W1, x, r1w1, r1b1, r1w2, r1b2, w_bs, b_bs, OUT, E);

    // K6, K7: in-place residual blocks on OUT
    res_kernel<<<gB, b512, 0, stream>>>(OUT, r2w1, r2b1, r2w2, r2b2, E);
    res_kernel<<<gB, b512, 0, stream>>>(OUT, r3w1, r3b1, r3w2, r3b2, E);
}